// Round 5
// baseline (705.167 us; speedup 1.0000x reference)
//
#include <hip/hip_runtime.h>
#include <cstdint>
#include <cstddef>

#define F_IN 128
#define NOUT 40
#define BN_EPS 1e-5f
#define RBITS 8
#define RSIZE 256           // nodes per range
#define MAXNR 512           // supports N <= 131072

typedef unsigned short u16;
typedef unsigned int u32;

static inline int ceil_div_l(long a, long b){ return (int)((a + b - 1) / b); }

__device__ __forceinline__ float4 f4zero(){ return make_float4(0.f,0.f,0.f,0.f); }
__device__ __forceinline__ float4 f4fma(float a, float4 b, float4 c){
  c.x = fmaf(a, b.x, c.x); c.y = fmaf(a, b.y, c.y);
  c.z = fmaf(a, b.z, c.z); c.w = fmaf(a, b.w, c.w); return c;
}
__device__ __forceinline__ float b2f(u16 h){
  union { u32 u; float f; } v; v.u = ((u32)h) << 16; return v.f;
}
__device__ __forceinline__ u16 f2b(float x){
  union { float f; u32 u; } v; v.f = x;
  u32 r = v.u + 0x7FFFu + ((v.u >> 16) & 1u);
  return (u16)(r >> 16);
}

// ---------- A1: per-range edge counts (LDS histogram) ----------
__global__ void k_rangecount(const int* __restrict__ dst, int* __restrict__ rangecnt,
                             int E, int NR, int chunk){
  __shared__ u32 hist[MAXNR];
  for (int i = threadIdx.x; i < NR; i += 256) hist[i] = 0;
  __syncthreads();
  int s = blockIdx.x * chunk;
  int e_end = min(s + chunk, E);
  for (int e = s + threadIdx.x; e < e_end; e += 256)
    atomicAdd(&hist[(u32)dst[e] >> RBITS], 1u);
  __syncthreads();
  for (int i = threadIdx.x; i < NR; i += 256){
    u32 h = hist[i];
    if (h) atomicAdd((u32*)&rangecnt[i], h);
  }
}

// ---------- A2: exclusive scan of range counts ----------
__global__ void k_rangescan(const int* __restrict__ rangecnt, int* __restrict__ rangebase,
                            int NR){
  __shared__ int s[MAXNR];
  int t = threadIdx.x;
  if (t < NR) s[t] = rangecnt[t];
  __syncthreads();
  if (t == 0){
    int acc = 0;
    for (int i = 0; i < NR; i++){ int v = s[i]; s[i] = acc; acc += v; }
  }
  __syncthreads();
  if (t < NR) rangebase[t] = s[t];
}

// ---------- A3: partition edges into per-range segments (packed u32) ----------
__global__ void k_partition(const int* __restrict__ src, const int* __restrict__ dst,
                            const int* __restrict__ rangebase, int* __restrict__ rangefill,
                            u32* __restrict__ part, int E, int NR, int chunk){
  __shared__ u32 hist[MAXNR];
  __shared__ u32 lbase[MAXNR];
  for (int i = threadIdx.x; i < NR; i += 256) hist[i] = 0;
  __syncthreads();
  int s0 = blockIdx.x * chunk;
  int e_end = min(s0 + chunk, E);
  for (int e = s0 + threadIdx.x; e < e_end; e += 256)
    atomicAdd(&hist[(u32)dst[e] >> RBITS], 1u);
  __syncthreads();
  for (int i = threadIdx.x; i < NR; i += 256){
    u32 h = hist[i];
    u32 b = h ? (u32)atomicAdd((u32*)&rangefill[i], h) : 0u;
    lbase[i] = (u32)rangebase[i] + b;
    hist[i] = 0;                       // reuse as local fill
  }
  __syncthreads();
  for (int e = s0 + threadIdx.x; e < e_end; e += 256){
    u32 d = (u32)dst[e];
    u32 r = d >> RBITS;
    u32 pos = lbase[r] + atomicAdd(&hist[r], 1u);
    part[pos] = (u32)src[e] | ((d & (RSIZE - 1)) << 17);
  }
}

// ---------- B: per-range CSR build + meta/dinv (all LDS atomics) ----------
__global__ void k_build(const u32* __restrict__ part, const int* __restrict__ rangecnt,
                        const int* __restrict__ rangebase, int4* __restrict__ meta,
                        float* __restrict__ dinv, int* __restrict__ csr, int n){
  __shared__ int hist[RSIZE];
  __shared__ int scanx[RSIZE];
  __shared__ int fill[RSIZE];
  int r = blockIdx.x;
  int ne = rangecnt[r], base = rangebase[r];
  int t = threadIdx.x;
  hist[t] = 0;
  __syncthreads();
  for (int i = t; i < ne; i += 256) atomicAdd(&hist[part[base + i] >> 17], 1);
  __syncthreads();
  int v = hist[t];
  scanx[t] = v;
  __syncthreads();
  for (int o = 1; o < 256; o <<= 1){
    int tv = (t >= o) ? scanx[t - o] : 0;
    __syncthreads();
    scanx[t] += tv;
    __syncthreads();
  }
  int excl = scanx[t] - v;
  int node = (r << RBITS) + t;
  if (node < n){
    float di = rsqrtf(1.0f + (float)v);
    meta[node] = make_int4(base + excl, v, __float_as_int(di), 0);
    dinv[node] = di;
  }
  fill[t] = 0;
  scanx[t] = excl;
  __syncthreads();
  for (int i = t; i < ne; i += 256){
    u32 p = part[base + i];
    int dl = (int)(p >> 17);
    int pos = scanx[dl] + atomicAdd(&fill[dl], 1);
    csr[base + pos] = (int)(p & 0x1FFFFu);
  }
}

// ---------- weighted edge list: ew[e] = (src, dinv[src]) ----------
__global__ void k_makeew(const int* __restrict__ csr, const float* __restrict__ dinv,
                         uint2* __restrict__ ew, int E){
  int e = blockIdx.x * 256 + threadIdx.x;
  if (e < E){
    int s = csr[e];
    ew[e] = make_uint2((u32)s, __float_as_uint(dinv[s]));
  }
}

// ---------- register-tiled GEMM, 128-row x 64-col tile, bf16 out ----------
template<bool XBF, bool BN>
__launch_bounds__(256, 2)
__global__ void k_gemm64(const void* __restrict__ Xv, const float* __restrict__ W,
                         int ldW, int wcols,
                         const float* __restrict__ scale, const float* __restrict__ shift,
                         u16* __restrict__ Y, int ldY, int col_off, int n, int ntiles){
  __shared__ float Wl[128 * 64];      // [k][c]
  __shared__ u16   Xl[128 * 136];     // [row][k], pad 136 -> conflict-free

  const int tid = threadIdx.x;
  for (int idx = tid; idx < 128 * 64; idx += 256){
    int k = idx >> 6, c = idx & 63;
    Wl[idx] = (c < wcols) ? W[(size_t)k * ldW + c] : 0.f;
  }

  float sc8[8], sh8[8];
  if (BN){
    int c0 = (tid & 15) << 3;
    #pragma unroll
    for (int j = 0; j < 8; j++){ sc8[j] = scale[c0 + j]; sh8[j] = shift[c0 + j]; }
  }

  const int tc = tid & 7;
  const int tr = tid >> 3;

  for (int t = blockIdx.x; t < ntiles; t += gridDim.x){
    const int r0 = t << 7;
    __syncthreads();
    for (int idx = tid; idx < 128 * 16; idx += 256){
      int row = idx >> 4, c8 = idx & 15;
      int gr = r0 + row;
      float x[8];
      if (gr < n){
        if (XBF){
          const u16* p = (const u16*)Xv + ((size_t)gr << 7) + (c8 << 3);
          uint4 u = *(const uint4*)p;
          x[0] = b2f((u16)u.x); x[1] = b2f((u16)(u.x >> 16));
          x[2] = b2f((u16)u.y); x[3] = b2f((u16)(u.y >> 16));
          x[4] = b2f((u16)u.z); x[5] = b2f((u16)(u.z >> 16));
          x[6] = b2f((u16)u.w); x[7] = b2f((u16)(u.w >> 16));
        } else {
          const float* p = (const float*)Xv + ((size_t)gr << 7) + (c8 << 3);
          float4 a = *(const float4*)p;
          float4 b = *(const float4*)(p + 4);
          x[0]=a.x; x[1]=a.y; x[2]=a.z; x[3]=a.w;
          x[4]=b.x; x[5]=b.y; x[6]=b.z; x[7]=b.w;
        }
        if (BN){
          #pragma unroll
          for (int j = 0; j < 8; j++)
            x[j] = fmaxf(fmaf(x[j], sc8[j], sh8[j]), 0.f);
        }
      } else {
        #pragma unroll
        for (int j = 0; j < 8; j++) x[j] = 0.f;
      }
      uint4 u;
      u.x = (u32)f2b(x[0]) | ((u32)f2b(x[1]) << 16);
      u.y = (u32)f2b(x[2]) | ((u32)f2b(x[3]) << 16);
      u.z = (u32)f2b(x[4]) | ((u32)f2b(x[5]) << 16);
      u.w = (u32)f2b(x[6]) | ((u32)f2b(x[7]) << 16);
      *(uint4*)(Xl + row * 136 + (c8 << 3)) = u;
    }
    __syncthreads();

    float4 acc[4][2];
    #pragma unroll
    for (int i = 0; i < 4; i++){ acc[i][0] = f4zero(); acc[i][1] = f4zero(); }

    for (int k8 = 0; k8 < 16; k8++){
      float xf[4][8];
      #pragma unroll
      for (int i = 0; i < 4; i++){
        uint4 u = *(const uint4*)(Xl + (tr + 32 * i) * 136 + (k8 << 3));
        xf[i][0] = b2f((u16)u.x); xf[i][1] = b2f((u16)(u.x >> 16));
        xf[i][2] = b2f((u16)u.y); xf[i][3] = b2f((u16)(u.y >> 16));
        xf[i][4] = b2f((u16)u.z); xf[i][5] = b2f((u16)(u.z >> 16));
        xf[i][6] = b2f((u16)u.w); xf[i][7] = b2f((u16)(u.w >> 16));
      }
      #pragma unroll
      for (int kk = 0; kk < 8; kk++){
        const float* wr = Wl + (((k8 << 3) + kk) << 6) + (tc << 2);
        float4 w0 = *(const float4*)wr;
        float4 w1 = *(const float4*)(wr + 32);
        #pragma unroll
        for (int i = 0; i < 4; i++){
          acc[i][0] = f4fma(xf[i][kk], w0, acc[i][0]);
          acc[i][1] = f4fma(xf[i][kk], w1, acc[i][1]);
        }
      }
    }

    #pragma unroll
    for (int i = 0; i < 4; i++){
      int row = r0 + tr + 32 * i;
      if (row < n){
        #pragma unroll
        for (int jq = 0; jq < 2; jq++){
          int cq = (tc << 2) + (jq << 5);
          if (cq < wcols){
            float4 a = acc[i][jq];
            ushort4 h;
            h.x = f2b(a.x); h.y = f2b(a.y); h.z = f2b(a.z); h.w = f2b(a.w);
            *(ushort4*)(Y + (size_t)row * ldY + col_off + cq) = h;
          }
        }
      }
    }
  }
}

// ---------- fused aggregation + BN stats (CSR gather, packed edges) ----------
__global__ void k_agg128(const u16* __restrict__ H, u16* __restrict__ Y,
                         const int4* __restrict__ meta, const uint2* __restrict__ ew,
                         float* __restrict__ gsum, float* __restrict__ gsq, int n){
  __shared__ float lsum[128], lsq[128];
  const int tid = threadIdx.x;
  if (tid < 128){ lsum[tid] = 0.f; lsq[tid] = 0.f; }
  __syncthreads();
  const int node = (blockIdx.x << 4) + (tid >> 4);
  const int c8 = tid & 15;
  if (node < n){
    const int4 m = meta[node];
    const int beg = m.x, num = m.y;
    const float di = __int_as_float(m.z);
    float acc[8];
    {
      uint4 u = *(const uint4*)(H + ((size_t)node << 7) + (c8 << 3));
      acc[0] = b2f((u16)u.x) * di; acc[1] = b2f((u16)(u.x >> 16)) * di;
      acc[2] = b2f((u16)u.y) * di; acc[3] = b2f((u16)(u.y >> 16)) * di;
      acc[4] = b2f((u16)u.z) * di; acc[5] = b2f((u16)(u.z >> 16)) * di;
      acc[6] = b2f((u16)u.w) * di; acc[7] = b2f((u16)(u.w >> 16)) * di;
    }
    int i = 0;
    if ((beg & 1) && num > 0){
      uint2 p = ew[beg];
      float w = __uint_as_float(p.y);
      uint4 u = *(const uint4*)(H + ((size_t)p.x << 7) + (c8 << 3));
      acc[0] = fmaf(b2f((u16)u.x),         w, acc[0]);
      acc[1] = fmaf(b2f((u16)(u.x >> 16)), w, acc[1]);
      acc[2] = fmaf(b2f((u16)u.y),         w, acc[2]);
      acc[3] = fmaf(b2f((u16)(u.y >> 16)), w, acc[3]);
      acc[4] = fmaf(b2f((u16)u.z),         w, acc[4]);
      acc[5] = fmaf(b2f((u16)(u.z >> 16)), w, acc[5]);
      acc[6] = fmaf(b2f((u16)u.w),         w, acc[6]);
      acc[7] = fmaf(b2f((u16)(u.w >> 16)), w, acc[7]);
      i = 1;
    }
    for (; i + 2 <= num; i += 2){
      uint4 p = *(const uint4*)(ew + beg + i);   // 16B-aligned (beg+i even)
      float w0 = __uint_as_float(p.y), w1 = __uint_as_float(p.w);
      uint4 a = *(const uint4*)(H + ((size_t)p.x << 7) + (c8 << 3));
      uint4 b = *(const uint4*)(H + ((size_t)p.z << 7) + (c8 << 3));
      acc[0] = fmaf(b2f((u16)a.x),         w0, acc[0]);
      acc[1] = fmaf(b2f((u16)(a.x >> 16)), w0, acc[1]);
      acc[2] = fmaf(b2f((u16)a.y),         w0, acc[2]);
      acc[3] = fmaf(b2f((u16)(a.y >> 16)), w0, acc[3]);
      acc[4] = fmaf(b2f((u16)a.z),         w0, acc[4]);
      acc[5] = fmaf(b2f((u16)(a.z >> 16)), w0, acc[5]);
      acc[6] = fmaf(b2f((u16)a.w),         w0, acc[6]);
      acc[7] = fmaf(b2f((u16)(a.w >> 16)), w0, acc[7]);
      acc[0] = fmaf(b2f((u16)b.x),         w1, acc[0]);
      acc[1] = fmaf(b2f((u16)(b.x >> 16)), w1, acc[1]);
      acc[2] = fmaf(b2f((u16)b.y),         w1, acc[2]);
      acc[3] = fmaf(b2f((u16)(b.y >> 16)), w1, acc[3]);
      acc[4] = fmaf(b2f((u16)b.z),         w1, acc[4]);
      acc[5] = fmaf(b2f((u16)(b.z >> 16)), w1, acc[5]);
      acc[6] = fmaf(b2f((u16)b.w),         w1, acc[6]);
      acc[7] = fmaf(b2f((u16)(b.w >> 16)), w1, acc[7]);
    }
    if (i < num){
      uint2 p = ew[beg + i];
      float w = __uint_as_float(p.y);
      uint4 u = *(const uint4*)(H + ((size_t)p.x << 7) + (c8 << 3));
      acc[0] = fmaf(b2f((u16)u.x),         w, acc[0]);
      acc[1] = fmaf(b2f((u16)(u.x >> 16)), w, acc[1]);
      acc[2] = fmaf(b2f((u16)u.y),         w, acc[2]);
      acc[3] = fmaf(b2f((u16)(u.y >> 16)), w, acc[3]);
      acc[4] = fmaf(b2f((u16)u.z),         w, acc[4]);
      acc[5] = fmaf(b2f((u16)(u.z >> 16)), w, acc[5]);
      acc[6] = fmaf(b2f((u16)u.w),         w, acc[6]);
      acc[7] = fmaf(b2f((u16)(u.w >> 16)), w, acc[7]);
    }
    #pragma unroll
    for (int j = 0; j < 8; j++) acc[j] *= di;
    // BN partials on fp32 pre-quantization values
    #pragma unroll
    for (int j = 0; j < 8; j++){
      atomicAdd(&lsum[(c8 << 3) + j], acc[j]);
      atomicAdd(&lsq [(c8 << 3) + j], acc[j] * acc[j]);
    }
    uint4 o;
    o.x = (u32)f2b(acc[0]) | ((u32)f2b(acc[1]) << 16);
    o.y = (u32)f2b(acc[2]) | ((u32)f2b(acc[3]) << 16);
    o.z = (u32)f2b(acc[4]) | ((u32)f2b(acc[5]) << 16);
    o.w = (u32)f2b(acc[6]) | ((u32)f2b(acc[7]) << 16);
    *(uint4*)(Y + ((size_t)node << 7) + (c8 << 3)) = o;
  }
  __syncthreads();
  if (tid < 128){
    const int sb = (blockIdx.x & 7) << 7;   // 8 stripes vs atomic contention
    atomicAdd(&gsum[sb + tid], lsum[tid]);
    atomicAdd(&gsq [sb + tid], lsq [tid]);
  }
}

__global__ void k_agg40(const u16* __restrict__ H, const float* __restrict__ bout,
                        float* __restrict__ Y, const int4* __restrict__ meta,
                        const uint2* __restrict__ ew, int n){
  int t = blockIdx.x * blockDim.x + threadIdx.x;
  int node = t >> 4, c4 = t & 15;
  if (node >= n || c4 >= 10) return;
  const int4 m = meta[node];
  const int beg = m.x, num = m.y;
  const float di = __int_as_float(m.z);
  float acc[4];
  {
    uint2 u = *(const uint2*)(H + (size_t)node * NOUT + (c4 << 2));
    acc[0] = b2f((u16)u.x) * di; acc[1] = b2f((u16)(u.x >> 16)) * di;
    acc[2] = b2f((u16)u.y) * di; acc[3] = b2f((u16)(u.y >> 16)) * di;
  }
  int i = 0;
  if ((beg & 1) && num > 0){
    uint2 p = ew[beg];
    float w = __uint_as_float(p.y);
    uint2 u = *(const uint2*)(H + (size_t)p.x * NOUT + (c4 << 2));
    acc[0] = fmaf(b2f((u16)u.x),         w, acc[0]);
    acc[1] = fmaf(b2f((u16)(u.x >> 16)), w, acc[1]);
    acc[2] = fmaf(b2f((u16)u.y),         w, acc[2]);
    acc[3] = fmaf(b2f((u16)(u.y >> 16)), w, acc[3]);
    i = 1;
  }
  for (; i + 2 <= num; i += 2){
    uint4 p = *(const uint4*)(ew + beg + i);
    float w0 = __uint_as_float(p.y), w1 = __uint_as_float(p.w);
    uint2 a = *(const uint2*)(H + (size_t)p.x * NOUT + (c4 << 2));
    uint2 b = *(const uint2*)(H + (size_t)p.z * NOUT + (c4 << 2));
    acc[0] = fmaf(b2f((u16)a.x),         w0, acc[0]);
    acc[1] = fmaf(b2f((u16)(a.x >> 16)), w0, acc[1]);
    acc[2] = fmaf(b2f((u16)a.y),         w0, acc[2]);
    acc[3] = fmaf(b2f((u16)(a.y >> 16)), w0, acc[3]);
    acc[0] = fmaf(b2f((u16)b.x),         w1, acc[0]);
    acc[1] = fmaf(b2f((u16)(b.x >> 16)), w1, acc[1]);
    acc[2] = fmaf(b2f((u16)b.y),         w1, acc[2]);
    acc[3] = fmaf(b2f((u16)(b.y >> 16)), w1, acc[3]);
  }
  if (i < num){
    uint2 p = ew[beg + i];
    float w = __uint_as_float(p.y);
    uint2 u = *(const uint2*)(H + (size_t)p.x * NOUT + (c4 << 2));
    acc[0] = fmaf(b2f((u16)u.x),         w, acc[0]);
    acc[1] = fmaf(b2f((u16)(u.x >> 16)), w, acc[1]);
    acc[2] = fmaf(b2f((u16)u.y),         w, acc[2]);
    acc[3] = fmaf(b2f((u16)(u.y >> 16)), w, acc[3]);
  }
  float4 bb = *(const float4*)(bout + (c4 << 2));
  float4 o;
  o.x = fmaf(acc[0], di, bb.x); o.y = fmaf(acc[1], di, bb.y);
  o.z = fmaf(acc[2], di, bb.z); o.w = fmaf(acc[3], di, bb.w);
  *(float4*)(Y + (size_t)node * NOUT + (c4 << 2)) = o;
}

// ---------- BN finalize (reduce 8 stripes) ----------
__global__ void k_bn_fin(const float* __restrict__ gsum, const float* __restrict__ gsq,
                         const float* __restrict__ g, const float* __restrict__ beta,
                         float* __restrict__ scale, float* __restrict__ shift, int n){
  int c = threadIdx.x;
  if (c < 128){
    float s = 0.f, q = 0.f;
    #pragma unroll
    for (int k = 0; k < 8; k++){ s += gsum[(k << 7) + c]; q += gsq[(k << 7) + c]; }
    float invn = 1.0f / (float)n;
    float mu  = s * invn;
    float var = q * invn - mu * mu;
    var = var > 0.f ? var : 0.f;
    float sc = g[c] * rsqrtf(var + BN_EPS);
    scale[c] = sc;
    shift[c] = beta[c] - mu * sc;
  }
}

// ---------- launch ----------
extern "C" void kernel_launch(void* const* d_in, const int* in_sizes, int n_in,
                              void* d_out, int out_size, void* d_ws, size_t ws_size,
                              hipStream_t stream) {
  const float* x0        = (const float*)d_in[0];
  const float* x1        = (const float*)d_in[1];
  const int*   ei        = (const int*)  d_in[2];
  const float* W_init    = (const float*)d_in[3];
  const float* g_init    = (const float*)d_in[5];
  const float* beta_init = (const float*)d_in[6];
  const float* W_mid     = (const float*)d_in[7];
  const float* g_mid     = (const float*)d_in[9];
  const float* beta_mid  = (const float*)d_in[10];
  const float* W_out     = (const float*)d_in[11];
  const float* b_out     = (const float*)d_in[12];

  int N = in_sizes[0] / F_IN;
  int E = in_sizes[2] / 2;
  const int* esrc = ei;
  const int* edst = ei + E;
  int NR = (N + RSIZE - 1) >> RBITS;

  char* w = (char*)d_ws;
  size_t off = 0;
  auto take = [&](size_t bytes) -> char* {
    char* p = w + off;
    off = (off + bytes + 255) & ~(size_t)255;
    return p;
  };
  float* dinv      = (float*)take((size_t)N * 4);
  int4*  meta      = (int4*) take((size_t)N * 16);
  int*   rangecnt  = (int*)  take((size_t)MAXNR * 4);
  int*   rangebase = (int*)  take((size_t)MAXNR * 4);
  int*   rangefill = (int*)  take((size_t)MAXNR * 4);
  float* stats     = (float*)take(4608 * 4);
  u32*   part      = (u32*)  take((size_t)E * 4);
  int*   csr       = (int*)  take((size_t)E * 4);
  uint2* ew        = (uint2*)take((size_t)E * 8);
  u16*   A         = (u16*)  take((size_t)N * 128 * 2);
  u16*   B         = (u16*)  take((size_t)N * 128 * 2);
  (void)ws_size; (void)n_in; (void)out_size;

  float* gsum1 = stats,        *gsq1 = stats + 1024, *scale1 = stats + 2048, *shift1 = stats + 2176;
  float* gsum2 = stats + 2304, *gsq2 = stats + 3328, *scale2 = stats + 4352, *shift2 = stats + 4480;

  hipMemsetAsync(rangecnt,  0, (size_t)MAXNR * 4, stream);
  hipMemsetAsync(rangefill, 0, (size_t)MAXNR * 4, stream);
  hipMemsetAsync(stats,     0, 4608 * 4, stream);

  // CSR build via range partition (no global per-edge atomics)
  const int PB = 512;
  const int chunk = ceil_div_l(E, PB);
  k_rangecount<<<PB, 256, 0, stream>>>(edst, rangecnt, E, NR, chunk);
  k_rangescan <<<1, MAXNR, 0, stream>>>(rangecnt, rangebase, NR);
  k_partition <<<PB, 256, 0, stream>>>(esrc, edst, rangebase, rangefill, part, E, NR, chunk);
  k_build     <<<NR, RSIZE, 0, stream>>>(part, rangecnt, rangebase, meta, dinv, csr, N);
  k_makeew    <<<ceil_div_l(E,256), 256, 0, stream>>>(csr, dinv, ew, E);

  const int ntiles = ceil_div_l(N, 128);
  const int GB = 512;                      // 2 blocks/CU
  const int AGB = ceil_div_l(N, 16);       // agg128 blocks

  // layer 1
  k_gemm64<false,false><<<GB,256,0,stream>>>(x0, W_init,           64, 64, nullptr, nullptr, A, 128,  0, N, ntiles);
  k_gemm64<false,false><<<GB,256,0,stream>>>(x1, W_init + 128*64,  64, 64, nullptr, nullptr, A, 128, 64, N, ntiles);
  k_agg128<<<AGB,256,0,stream>>>(A, B, meta, ew, gsum1, gsq1, N);
  k_bn_fin<<<1,128,0,stream>>>(gsum1, gsq1, g_init, beta_init, scale1, shift1, N);

  // layer 2
  k_gemm64<true,true><<<GB,256,0,stream>>>(B, W_mid,      128, 64, scale1, shift1, A, 128,  0, N, ntiles);
  k_gemm64<true,true><<<GB,256,0,stream>>>(B, W_mid + 64, 128, 64, scale1, shift1, A, 128, 64, N, ntiles);
  k_agg128<<<AGB,256,0,stream>>>(A, B, meta, ew, gsum2, gsq2, N);
  k_bn_fin<<<1,128,0,stream>>>(gsum2, gsq2, g_mid, beta_mid, scale2, shift2, N);

  // layer 3
  k_gemm64<true,true><<<GB,256,0,stream>>>(B, W_out, 40, 40, scale2, shift2, A, 40, 0, N, ntiles);
  k_agg40<<<ceil_div_l((long)N*16,256),256,0,stream>>>(A, b_out, (float*)d_out, meta, ew, N);
}

// Round 6
// 556.219 us; speedup vs baseline: 1.2678x; 1.2678x over previous
//
#include <hip/hip_runtime.h>
#include <cstdint>
#include <cstddef>

#define F_IN 128
#define NOUT 40
#define BN_EPS 1e-5f
#define RBITS 8
#define RSIZE 256           // nodes per range
#define MAXNR 512           // supports N <= 131072
#define DBINS 64            // degree-sort bins (cap 63)

typedef unsigned short u16;
typedef unsigned int u32;

static inline int ceil_div_l(long a, long b){ return (int)((a + b - 1) / b); }

__device__ __forceinline__ float4 f4zero(){ return make_float4(0.f,0.f,0.f,0.f); }
__device__ __forceinline__ float4 f4fma(float a, float4 b, float4 c){
  c.x = fmaf(a, b.x, c.x); c.y = fmaf(a, b.y, c.y);
  c.z = fmaf(a, b.z, c.z); c.w = fmaf(a, b.w, c.w); return c;
}
__device__ __forceinline__ float b2f(u16 h){
  union { u32 u; float f; } v; v.u = ((u32)h) << 16; return v.f;
}
__device__ __forceinline__ u16 f2b(float x){
  union { float f; u32 u; } v; v.f = x;
  u32 r = v.u + 0x7FFFu + ((v.u >> 16) & 1u);
  return (u16)(r >> 16);
}
__device__ __forceinline__ void acc8(float* acc, uint4 u, float w){
  acc[0] = fmaf(b2f((u16)u.x),         w, acc[0]);
  acc[1] = fmaf(b2f((u16)(u.x >> 16)), w, acc[1]);
  acc[2] = fmaf(b2f((u16)u.y),         w, acc[2]);
  acc[3] = fmaf(b2f((u16)(u.y >> 16)), w, acc[3]);
  acc[4] = fmaf(b2f((u16)u.z),         w, acc[4]);
  acc[5] = fmaf(b2f((u16)(u.z >> 16)), w, acc[5]);
  acc[6] = fmaf(b2f((u16)u.w),         w, acc[6]);
  acc[7] = fmaf(b2f((u16)(u.w >> 16)), w, acc[7]);
}
__device__ __forceinline__ void acc4(float* acc, uint2 u, float w){
  acc[0] = fmaf(b2f((u16)u.x),         w, acc[0]);
  acc[1] = fmaf(b2f((u16)(u.x >> 16)), w, acc[1]);
  acc[2] = fmaf(b2f((u16)u.y),         w, acc[2]);
  acc[3] = fmaf(b2f((u16)(u.y >> 16)), w, acc[3]);
}

// ---------- A1: per-range edge counts (LDS histogram) ----------
__global__ void k_rangecount(const int* __restrict__ dst, int* __restrict__ rangecnt,
                             int E, int NR, int chunk){
  __shared__ u32 hist[MAXNR];
  for (int i = threadIdx.x; i < NR; i += 256) hist[i] = 0;
  __syncthreads();
  int s = blockIdx.x * chunk;
  int e_end = min(s + chunk, E);
  for (int e = s + threadIdx.x; e < e_end; e += 256)
    atomicAdd(&hist[(u32)dst[e] >> RBITS], 1u);
  __syncthreads();
  for (int i = threadIdx.x; i < NR; i += 256){
    u32 h = hist[i];
    if (h) atomicAdd((u32*)&rangecnt[i], h);
  }
}

// ---------- A2: exclusive scan of range counts ----------
__global__ void k_rangescan(const int* __restrict__ rangecnt, int* __restrict__ rangebase,
                            int NR){
  __shared__ int s[MAXNR];
  int t = threadIdx.x;
  if (t < NR) s[t] = rangecnt[t];
  __syncthreads();
  if (t == 0){
    int acc = 0;
    for (int i = 0; i < NR; i++){ int v = s[i]; s[i] = acc; acc += v; }
  }
  __syncthreads();
  if (t < NR) rangebase[t] = s[t];
}

// ---------- A3: partition edges into per-range segments (packed u32) ----------
__global__ void k_partition(const int* __restrict__ src, const int* __restrict__ dst,
                            const int* __restrict__ rangebase, int* __restrict__ rangefill,
                            u32* __restrict__ part, int E, int NR, int chunk){
  __shared__ u32 hist[MAXNR];
  __shared__ u32 lbase[MAXNR];
  for (int i = threadIdx.x; i < NR; i += 256) hist[i] = 0;
  __syncthreads();
  int s0 = blockIdx.x * chunk;
  int e_end = min(s0 + chunk, E);
  for (int e = s0 + threadIdx.x; e < e_end; e += 256)
    atomicAdd(&hist[(u32)dst[e] >> RBITS], 1u);
  __syncthreads();
  for (int i = threadIdx.x; i < NR; i += 256){
    u32 h = hist[i];
    u32 b = h ? (u32)atomicAdd((u32*)&rangefill[i], h) : 0u;
    lbase[i] = (u32)rangebase[i] + b;
    hist[i] = 0;                       // reuse as local fill
  }
  __syncthreads();
  for (int e = s0 + threadIdx.x; e < e_end; e += 256){
    u32 d = (u32)dst[e];
    u32 r = d >> RBITS;
    u32 pos = lbase[r] + atomicAdd(&hist[r], 1u);
    part[pos] = (u32)src[e] | ((d & (RSIZE - 1)) << 17);
  }
}

// ---------- B: per-range CSR build + meta/dinv (all LDS atomics) ----------
__global__ void k_build(const u32* __restrict__ part, const int* __restrict__ rangecnt,
                        const int* __restrict__ rangebase, int4* __restrict__ meta,
                        float* __restrict__ dinv, int* __restrict__ csr, int n){
  __shared__ int hist[RSIZE];
  __shared__ int scanx[RSIZE];
  __shared__ int fill[RSIZE];
  int r = blockIdx.x;
  int ne = rangecnt[r], base = rangebase[r];
  int t = threadIdx.x;
  hist[t] = 0;
  __syncthreads();
  for (int i = t; i < ne; i += 256) atomicAdd(&hist[part[base + i] >> 17], 1);
  __syncthreads();
  int v = hist[t];
  scanx[t] = v;
  __syncthreads();
  for (int o = 1; o < 256; o <<= 1){
    int tv = (t >= o) ? scanx[t - o] : 0;
    __syncthreads();
    scanx[t] += tv;
    __syncthreads();
  }
  int excl = scanx[t] - v;
  int node = (r << RBITS) + t;
  if (node < n){
    float di = rsqrtf(1.0f + (float)v);
    meta[node] = make_int4(base + excl, v, __float_as_int(di), 0);
    dinv[node] = di;
  }
  fill[t] = 0;
  scanx[t] = excl;
  __syncthreads();
  for (int i = t; i < ne; i += 256){
    u32 p = part[base + i];
    int dl = (int)(p >> 17);
    int pos = scanx[dl] + atomicAdd(&fill[dl], 1);
    csr[base + pos] = (int)(p & 0x1FFFFu);
  }
}

// ---------- weighted edge list: ew[e] = (src, dinv[src]) ----------
__global__ void k_makeew(const int* __restrict__ csr, const float* __restrict__ dinv,
                         uint2* __restrict__ ew, int E){
  int e = blockIdx.x * 256 + threadIdx.x;
  if (e < E){
    int s = csr[e];
    ew[e] = make_uint2((u32)s, __float_as_uint(dinv[s]));
  }
}

// ---------- degree-sorted node permutation (counting sort, LDS-batched) ----------
__global__ void k_deghist(const int4* __restrict__ meta, int* __restrict__ dhist, int n){
  __shared__ int h[DBINS];
  if (threadIdx.x < DBINS) h[threadIdx.x] = 0;
  __syncthreads();
  int i = blockIdx.x * 256 + threadIdx.x;
  if (i < n) atomicAdd(&h[min(meta[i].y, DBINS - 1)], 1);
  __syncthreads();
  if (threadIdx.x < DBINS && h[threadIdx.x])
    atomicAdd(&dhist[threadIdx.x], h[threadIdx.x]);
}

__global__ void k_degscan(const int* __restrict__ dhist, int* __restrict__ dbase){
  if (threadIdx.x == 0){
    int acc = 0;
    for (int i = 0; i < DBINS; i++){ dbase[i] = acc; acc += dhist[i]; }
  }
}

__global__ void k_degplace(const int4* __restrict__ meta, const int* __restrict__ dbase,
                           int* __restrict__ dfill, int* __restrict__ perm, int n){
  __shared__ int h[DBINS], lbase[DBINS];
  if (threadIdx.x < DBINS) h[threadIdx.x] = 0;
  __syncthreads();
  int i = blockIdx.x * 256 + threadIdx.x;
  int d = 0;
  if (i < n){
    d = min(meta[i].y, DBINS - 1);
    atomicAdd(&h[d], 1);
  }
  __syncthreads();
  if (threadIdx.x < DBINS){
    int c = h[threadIdx.x];
    lbase[threadIdx.x] = c ? dbase[threadIdx.x] + atomicAdd(&dfill[threadIdx.x], c) : 0;
    h[threadIdx.x] = 0;
  }
  __syncthreads();
  if (i < n){
    int pos = lbase[d] + atomicAdd(&h[d], 1);
    perm[pos] = i;
  }
}

// ---------- register-tiled GEMM, 128-row x 64-col tile, bf16 out ----------
template<bool XBF, bool BN>
__launch_bounds__(256, 2)
__global__ void k_gemm64(const void* __restrict__ Xv, const float* __restrict__ W,
                         int ldW, int wcols,
                         const float* __restrict__ scale, const float* __restrict__ shift,
                         u16* __restrict__ Y, int ldY, int col_off, int n, int ntiles){
  __shared__ float Wl[128 * 64];      // [k][c]
  __shared__ u16   Xl[128 * 136];     // [row][k], pad 136 -> conflict-free

  const int tid = threadIdx.x;
  for (int idx = tid; idx < 128 * 64; idx += 256){
    int k = idx >> 6, c = idx & 63;
    Wl[idx] = (c < wcols) ? W[(size_t)k * ldW + c] : 0.f;
  }

  float sc8[8], sh8[8];
  if (BN){
    int c0 = (tid & 15) << 3;
    #pragma unroll
    for (int j = 0; j < 8; j++){ sc8[j] = scale[c0 + j]; sh8[j] = shift[c0 + j]; }
  }

  const int tc = tid & 7;
  const int tr = tid >> 3;

  for (int t = blockIdx.x; t < ntiles; t += gridDim.x){
    const int r0 = t << 7;
    __syncthreads();
    for (int idx = tid; idx < 128 * 16; idx += 256){
      int row = idx >> 4, c8 = idx & 15;
      int gr = r0 + row;
      float x[8];
      if (gr < n){
        if (XBF){
          const u16* p = (const u16*)Xv + ((size_t)gr << 7) + (c8 << 3);
          uint4 u = *(const uint4*)p;
          x[0] = b2f((u16)u.x); x[1] = b2f((u16)(u.x >> 16));
          x[2] = b2f((u16)u.y); x[3] = b2f((u16)(u.y >> 16));
          x[4] = b2f((u16)u.z); x[5] = b2f((u16)(u.z >> 16));
          x[6] = b2f((u16)u.w); x[7] = b2f((u16)(u.w >> 16));
        } else {
          const float* p = (const float*)Xv + ((size_t)gr << 7) + (c8 << 3);
          float4 a = *(const float4*)p;
          float4 b = *(const float4*)(p + 4);
          x[0]=a.x; x[1]=a.y; x[2]=a.z; x[3]=a.w;
          x[4]=b.x; x[5]=b.y; x[6]=b.z; x[7]=b.w;
        }
        if (BN){
          #pragma unroll
          for (int j = 0; j < 8; j++)
            x[j] = fmaxf(fmaf(x[j], sc8[j], sh8[j]), 0.f);
        }
      } else {
        #pragma unroll
        for (int j = 0; j < 8; j++) x[j] = 0.f;
      }
      uint4 u;
      u.x = (u32)f2b(x[0]) | ((u32)f2b(x[1]) << 16);
      u.y = (u32)f2b(x[2]) | ((u32)f2b(x[3]) << 16);
      u.z = (u32)f2b(x[4]) | ((u32)f2b(x[5]) << 16);
      u.w = (u32)f2b(x[6]) | ((u32)f2b(x[7]) << 16);
      *(uint4*)(Xl + row * 136 + (c8 << 3)) = u;
    }
    __syncthreads();

    float4 acc[4][2];
    #pragma unroll
    for (int i = 0; i < 4; i++){ acc[i][0] = f4zero(); acc[i][1] = f4zero(); }

    for (int k8 = 0; k8 < 16; k8++){
      float xf[4][8];
      #pragma unroll
      for (int i = 0; i < 4; i++){
        uint4 u = *(const uint4*)(Xl + (tr + 32 * i) * 136 + (k8 << 3));
        xf[i][0] = b2f((u16)u.x); xf[i][1] = b2f((u16)(u.x >> 16));
        xf[i][2] = b2f((u16)u.y); xf[i][3] = b2f((u16)(u.y >> 16));
        xf[i][4] = b2f((u16)u.z); xf[i][5] = b2f((u16)(u.z >> 16));
        xf[i][6] = b2f((u16)u.w); xf[i][7] = b2f((u16)(u.w >> 16));
      }
      #pragma unroll
      for (int kk = 0; kk < 8; kk++){
        const float* wr = Wl + (((k8 << 3) + kk) << 6) + (tc << 2);
        float4 w0 = *(const float4*)wr;
        float4 w1 = *(const float4*)(wr + 32);
        #pragma unroll
        for (int i = 0; i < 4; i++){
          acc[i][0] = f4fma(xf[i][kk], w0, acc[i][0]);
          acc[i][1] = f4fma(xf[i][kk], w1, acc[i][1]);
        }
      }
    }

    #pragma unroll
    for (int i = 0; i < 4; i++){
      int row = r0 + tr + 32 * i;
      if (row < n){
        #pragma unroll
        for (int jq = 0; jq < 2; jq++){
          int cq = (tc << 2) + (jq << 5);
          if (cq < wcols){
            float4 a = acc[i][jq];
            ushort4 h;
            h.x = f2b(a.x); h.y = f2b(a.y); h.z = f2b(a.z); h.w = f2b(a.w);
            *(ushort4*)(Y + (size_t)row * ldY + col_off + cq) = h;
          }
        }
      }
    }
  }
}

// ---------- aggregation (CSR gather, packed edges, degree-sorted order) ----------
__global__ void k_agg128(const u16* __restrict__ H, u16* __restrict__ Y,
                         const int4* __restrict__ meta, const uint2* __restrict__ ew,
                         const int* __restrict__ perm, int n){
  int t = blockIdx.x * 256 + threadIdx.x;
  int g = t >> 4, c8 = t & 15;
  if (g >= n) return;
  const int node = perm[g];
  const int4 m = meta[node];
  const int beg = m.x, num = m.y;
  const float di = __int_as_float(m.z);
  float acc[8];
  {
    uint4 u = *(const uint4*)(H + ((size_t)node << 7) + (c8 << 3));
    acc[0] = b2f((u16)u.x) * di; acc[1] = b2f((u16)(u.x >> 16)) * di;
    acc[2] = b2f((u16)u.y) * di; acc[3] = b2f((u16)(u.y >> 16)) * di;
    acc[4] = b2f((u16)u.z) * di; acc[5] = b2f((u16)(u.z >> 16)) * di;
    acc[6] = b2f((u16)u.w) * di; acc[7] = b2f((u16)(u.w >> 16)) * di;
  }
  int i = 0;
  if ((beg & 1) && num > 0){           // align to even for uint4 ew loads
    uint2 p = ew[beg];
    acc8(acc, *(const uint4*)(H + ((size_t)p.x << 7) + (c8 << 3)), __uint_as_float(p.y));
    i = 1;
  }
  for (; i + 4 <= num; i += 4){
    uint4 p = *(const uint4*)(ew + beg + i);
    uint4 q = *(const uint4*)(ew + beg + i + 2);
    uint4 a = *(const uint4*)(H + ((size_t)p.x << 7) + (c8 << 3));
    uint4 b = *(const uint4*)(H + ((size_t)p.z << 7) + (c8 << 3));
    uint4 c = *(const uint4*)(H + ((size_t)q.x << 7) + (c8 << 3));
    uint4 d = *(const uint4*)(H + ((size_t)q.z << 7) + (c8 << 3));
    acc8(acc, a, __uint_as_float(p.y));
    acc8(acc, b, __uint_as_float(p.w));
    acc8(acc, c, __uint_as_float(q.y));
    acc8(acc, d, __uint_as_float(q.w));
  }
  if (i + 2 <= num){
    uint4 p = *(const uint4*)(ew + beg + i);
    uint4 a = *(const uint4*)(H + ((size_t)p.x << 7) + (c8 << 3));
    uint4 b = *(const uint4*)(H + ((size_t)p.z << 7) + (c8 << 3));
    acc8(acc, a, __uint_as_float(p.y));
    acc8(acc, b, __uint_as_float(p.w));
    i += 2;
  }
  if (i < num){
    uint2 p = ew[beg + i];
    acc8(acc, *(const uint4*)(H + ((size_t)p.x << 7) + (c8 << 3)), __uint_as_float(p.y));
  }
  uint4 o;
  o.x = (u32)f2b(acc[0] * di) | ((u32)f2b(acc[1] * di) << 16);
  o.y = (u32)f2b(acc[2] * di) | ((u32)f2b(acc[3] * di) << 16);
  o.z = (u32)f2b(acc[4] * di) | ((u32)f2b(acc[5] * di) << 16);
  o.w = (u32)f2b(acc[6] * di) | ((u32)f2b(acc[7] * di) << 16);
  *(uint4*)(Y + ((size_t)node << 7) + (c8 << 3)) = o;
}

__global__ void k_agg40(const u16* __restrict__ H, const float* __restrict__ bout,
                        float* __restrict__ Y, const int4* __restrict__ meta,
                        const uint2* __restrict__ ew, const int* __restrict__ perm, int n){
  int t = blockIdx.x * 256 + threadIdx.x;
  int g = t >> 4, c4 = t & 15;
  if (g >= n || c4 >= 10) return;
  const int node = perm[g];
  const int4 m = meta[node];
  const int beg = m.x, num = m.y;
  const float di = __int_as_float(m.z);
  float acc[4];
  {
    uint2 u = *(const uint2*)(H + (size_t)node * NOUT + (c4 << 2));
    acc[0] = b2f((u16)u.x) * di; acc[1] = b2f((u16)(u.x >> 16)) * di;
    acc[2] = b2f((u16)u.y) * di; acc[3] = b2f((u16)(u.y >> 16)) * di;
  }
  int i = 0;
  if ((beg & 1) && num > 0){
    uint2 p = ew[beg];
    acc4(acc, *(const uint2*)(H + (size_t)p.x * NOUT + (c4 << 2)), __uint_as_float(p.y));
    i = 1;
  }
  for (; i + 2 <= num; i += 2){
    uint4 p = *(const uint4*)(ew + beg + i);
    uint2 a = *(const uint2*)(H + (size_t)p.x * NOUT + (c4 << 2));
    uint2 b = *(const uint2*)(H + (size_t)p.z * NOUT + (c4 << 2));
    acc4(acc, a, __uint_as_float(p.y));
    acc4(acc, b, __uint_as_float(p.w));
  }
  if (i < num){
    uint2 p = ew[beg + i];
    acc4(acc, *(const uint2*)(H + (size_t)p.x * NOUT + (c4 << 2)), __uint_as_float(p.y));
  }
  float4 bb = *(const float4*)(bout + (c4 << 2));
  float4 o;
  o.x = fmaf(acc[0], di, bb.x); o.y = fmaf(acc[1], di, bb.y);
  o.z = fmaf(acc[2], di, bb.z); o.w = fmaf(acc[3], di, bb.w);
  *(float4*)(Y + (size_t)node * NOUT + (c4 << 2)) = o;
}

// ---------- BatchNorm stats (bf16 input) ----------
__global__ void k_bn_stats(const u16* __restrict__ X, float* __restrict__ sum,
                           float* __restrict__ sq, int n){
  int c = threadIdx.x & 127, half = threadIdx.x >> 7;
  float s = 0.f, q = 0.f;
  for (int r = blockIdx.x * 2 + half; r < n; r += gridDim.x * 2){
    float v = b2f(X[((size_t)r << 7) + c]);
    s += v; q = fmaf(v, v, q);
  }
  __shared__ float ls[256], lq[256];
  ls[threadIdx.x] = s; lq[threadIdx.x] = q;
  __syncthreads();
  if (threadIdx.x < 128){
    s = ls[threadIdx.x] + ls[threadIdx.x + 128];
    q = lq[threadIdx.x] + lq[threadIdx.x + 128];
    atomicAdd(&sum[c], s); atomicAdd(&sq[c], q);
  }
}

__global__ void k_bn_fin(const float* __restrict__ sum, const float* __restrict__ sq,
                         const float* __restrict__ g, const float* __restrict__ beta,
                         float* __restrict__ scale, float* __restrict__ shift, int n){
  int c = threadIdx.x;
  if (c < 128){
    float invn = 1.0f / (float)n;
    float mu  = sum[c] * invn;
    float var = sq[c] * invn - mu * mu;
    var = var > 0.f ? var : 0.f;
    float sc = g[c] * rsqrtf(var + BN_EPS);
    scale[c] = sc;
    shift[c] = beta[c] - mu * sc;
  }
}

// ---------- launch ----------
extern "C" void kernel_launch(void* const* d_in, const int* in_sizes, int n_in,
                              void* d_out, int out_size, void* d_ws, size_t ws_size,
                              hipStream_t stream) {
  const float* x0        = (const float*)d_in[0];
  const float* x1        = (const float*)d_in[1];
  const int*   ei        = (const int*)  d_in[2];
  const float* W_init    = (const float*)d_in[3];
  const float* g_init    = (const float*)d_in[5];
  const float* beta_init = (const float*)d_in[6];
  const float* W_mid     = (const float*)d_in[7];
  const float* g_mid     = (const float*)d_in[9];
  const float* beta_mid  = (const float*)d_in[10];
  const float* W_out     = (const float*)d_in[11];
  const float* b_out     = (const float*)d_in[12];

  int N = in_sizes[0] / F_IN;
  int E = in_sizes[2] / 2;
  const int* esrc = ei;
  const int* edst = ei + E;
  int NR = (N + RSIZE - 1) >> RBITS;

  char* w = (char*)d_ws;
  size_t off = 0;
  auto take = [&](size_t bytes) -> char* {
    char* p = w + off;
    off = (off + bytes + 255) & ~(size_t)255;
    return p;
  };
  float* dinv      = (float*)take((size_t)N * 4);
  int4*  meta      = (int4*) take((size_t)N * 16);
  int*   perm      = (int*)  take((size_t)N * 4);
  int*   rangecnt  = (int*)  take((size_t)MAXNR * 4);
  int*   rangebase = (int*)  take((size_t)MAXNR * 4);
  int*   rangefill = (int*)  take((size_t)MAXNR * 4);
  int*   dhist     = (int*)  take((size_t)DBINS * 4);
  int*   dbase     = (int*)  take((size_t)DBINS * 4);
  int*   dfill     = (int*)  take((size_t)DBINS * 4);
  float* stats     = (float*)take(1024 * 4);
  u32*   part      = (u32*)  take((size_t)E * 4);
  int*   csr       = (int*)  take((size_t)E * 4);
  uint2* ew        = (uint2*)take((size_t)E * 8);
  u16*   A         = (u16*)  take((size_t)N * 128 * 2);
  u16*   B         = (u16*)  take((size_t)N * 128 * 2);
  (void)ws_size; (void)n_in; (void)out_size;

  float* sum1 = stats,       *sq1 = stats + 128, *scale1 = stats + 256, *shift1 = stats + 384;
  float* sum2 = stats + 512, *sq2 = stats + 640, *scale2 = stats + 768, *shift2 = stats + 896;

  hipMemsetAsync(rangecnt,  0, (size_t)MAXNR * 4, stream);
  hipMemsetAsync(rangefill, 0, (size_t)MAXNR * 4, stream);
  hipMemsetAsync(dhist,     0, (size_t)DBINS * 4, stream);
  hipMemsetAsync(dfill,     0, (size_t)DBINS * 4, stream);
  hipMemsetAsync(stats,     0, 1024 * 4, stream);

  // CSR build via range partition (no global per-edge atomics)
  const int PB = 512;
  const int chunk = ceil_div_l(E, PB);
  const int NBn = ceil_div_l(N, 256);
  k_rangecount<<<PB, 256, 0, stream>>>(edst, rangecnt, E, NR, chunk);
  k_rangescan <<<1, MAXNR, 0, stream>>>(rangecnt, rangebase, NR);
  k_partition <<<PB, 256, 0, stream>>>(esrc, edst, rangebase, rangefill, part, E, NR, chunk);
  k_build     <<<NR, RSIZE, 0, stream>>>(part, rangecnt, rangebase, meta, dinv, csr, N);
  k_makeew    <<<ceil_div_l(E,256), 256, 0, stream>>>(csr, dinv, ew, E);
  // degree-sorted permutation (equal-degree nodes share a wave -> no divergence waste)
  k_deghist <<<NBn, 256, 0, stream>>>(meta, dhist, N);
  k_degscan <<<1, 64, 0, stream>>>(dhist, dbase);
  k_degplace<<<NBn, 256, 0, stream>>>(meta, dbase, dfill, perm, N);

  const int ntiles = ceil_div_l(N, 128);
  const int GB = 512;                      // 2 blocks/CU
  const int AGB = ceil_div_l(N, 16);       // agg blocks (16 nodes x 16 lanes)

  // layer 1
  k_gemm64<false,false><<<GB,256,0,stream>>>(x0, W_init,           64, 64, nullptr, nullptr, A, 128,  0, N, ntiles);
  k_gemm64<false,false><<<GB,256,0,stream>>>(x1, W_init + 128*64,  64, 64, nullptr, nullptr, A, 128, 64, N, ntiles);
  k_agg128<<<AGB,256,0,stream>>>(A, B, meta, ew, perm, N);
  k_bn_stats<<<512,256,0,stream>>>(B, sum1, sq1, N);
  k_bn_fin<<<1,128,0,stream>>>(sum1, sq1, g_init, beta_init, scale1, shift1, N);

  // layer 2
  k_gemm64<true,true><<<GB,256,0,stream>>>(B, W_mid,      128, 64, scale1, shift1, A, 128,  0, N, ntiles);
  k_gemm64<true,true><<<GB,256,0,stream>>>(B, W_mid + 64, 128, 64, scale1, shift1, A, 128, 64, N, ntiles);
  k_agg128<<<AGB,256,0,stream>>>(A, B, meta, ew, perm, N);
  k_bn_stats<<<512,256,0,stream>>>(B, sum2, sq2, N);
  k_bn_fin<<<1,128,0,stream>>>(sum2, sq2, g_mid, beta_mid, scale2, shift2, N);

  // layer 3
  k_gemm64<true,true><<<GB,256,0,stream>>>(B, W_out, 40, 40, scale2, shift2, A, 40, 0, N, ntiles);
  k_agg40<<<AGB,256,0,stream>>>(A, b_out, (float*)d_out, meta, ew, perm, N);
}

// Round 7
// 412.070 us; speedup vs baseline: 1.7113x; 1.3498x over previous
//
#include <hip/hip_runtime.h>
#include <cstdint>
#include <cstddef>

#define F_IN 128
#define NOUT 40
#define BN_EPS 1e-5f
#define RBITS 8
#define RSIZE 256           // nodes per range
#define MAXNR 512           // supports N <= 131072
#define DBINS 64            // degree-sort bins (cap 63)

typedef unsigned short u16;
typedef unsigned int u32;
typedef __attribute__((ext_vector_type(8))) short short8v;  // 8 bf16 (4 VGPR)
typedef __attribute__((ext_vector_type(4))) float f32x4;

static inline int ceil_div_l(long a, long b){ return (int)((a + b - 1) / b); }

__device__ __forceinline__ float b2f(u16 h){
  union { u32 u; float f; } v; v.u = ((u32)h) << 16; return v.f;
}
__device__ __forceinline__ u16 f2b(float x){
  union { float f; u32 u; } v; v.f = x;
  u32 r = v.u + 0x7FFFu + ((v.u >> 16) & 1u);
  return (u16)(r >> 16);
}
__device__ __forceinline__ void acc8(float* acc, uint4 u, float w){
  acc[0] = fmaf(b2f((u16)u.x),         w, acc[0]);
  acc[1] = fmaf(b2f((u16)(u.x >> 16)), w, acc[1]);
  acc[2] = fmaf(b2f((u16)u.y),         w, acc[2]);
  acc[3] = fmaf(b2f((u16)(u.y >> 16)), w, acc[3]);
  acc[4] = fmaf(b2f((u16)u.z),         w, acc[4]);
  acc[5] = fmaf(b2f((u16)(u.z >> 16)), w, acc[5]);
  acc[6] = fmaf(b2f((u16)u.w),         w, acc[6]);
  acc[7] = fmaf(b2f((u16)(u.w >> 16)), w, acc[7]);
}
__device__ __forceinline__ void acc4(float* acc, uint2 u, float w){
  acc[0] = fmaf(b2f((u16)u.x),         w, acc[0]);
  acc[1] = fmaf(b2f((u16)(u.x >> 16)), w, acc[1]);
  acc[2] = fmaf(b2f((u16)u.y),         w, acc[2]);
  acc[3] = fmaf(b2f((u16)(u.y >> 16)), w, acc[3]);
}

// ---------- A1: per-range edge counts (LDS histogram) ----------
__global__ void k_rangecount(const int* __restrict__ dst, int* __restrict__ rangecnt,
                             int E, int NR, int chunk){
  __shared__ u32 hist[MAXNR];
  for (int i = threadIdx.x; i < NR; i += 256) hist[i] = 0;
  __syncthreads();
  int s = blockIdx.x * chunk;
  int e_end = min(s + chunk, E);
  for (int e = s + threadIdx.x; e < e_end; e += 256)
    atomicAdd(&hist[(u32)dst[e] >> RBITS], 1u);
  __syncthreads();
  for (int i = threadIdx.x; i < NR; i += 256){
    u32 h = hist[i];
    if (h) atomicAdd((u32*)&rangecnt[i], h);
  }
}

// ---------- A2: exclusive scan of range counts ----------
__global__ void k_rangescan(const int* __restrict__ rangecnt, int* __restrict__ rangebase,
                            int NR){
  __shared__ int s[MAXNR];
  int t = threadIdx.x;
  if (t < NR) s[t] = rangecnt[t];
  __syncthreads();
  if (t == 0){
    int acc = 0;
    for (int i = 0; i < NR; i++){ int v = s[i]; s[i] = acc; acc += v; }
  }
  __syncthreads();
  if (t < NR) rangebase[t] = s[t];
}

// ---------- A3: partition edges into per-range segments (packed u32) ----------
__global__ void k_partition(const int* __restrict__ src, const int* __restrict__ dst,
                            const int* __restrict__ rangebase, int* __restrict__ rangefill,
                            u32* __restrict__ part, int E, int NR, int chunk){
  __shared__ u32 hist[MAXNR];
  __shared__ u32 lbase[MAXNR];
  for (int i = threadIdx.x; i < NR; i += 256) hist[i] = 0;
  __syncthreads();
  int s0 = blockIdx.x * chunk;
  int e_end = min(s0 + chunk, E);
  for (int e = s0 + threadIdx.x; e < e_end; e += 256)
    atomicAdd(&hist[(u32)dst[e] >> RBITS], 1u);
  __syncthreads();
  for (int i = threadIdx.x; i < NR; i += 256){
    u32 h = hist[i];
    u32 b = h ? (u32)atomicAdd((u32*)&rangefill[i], h) : 0u;
    lbase[i] = (u32)rangebase[i] + b;
    hist[i] = 0;                       // reuse as local fill
  }
  __syncthreads();
  for (int e = s0 + threadIdx.x; e < e_end; e += 256){
    u32 d = (u32)dst[e];
    u32 r = d >> RBITS;
    u32 pos = lbase[r] + atomicAdd(&hist[r], 1u);
    part[pos] = (u32)src[e] | ((d & (RSIZE - 1)) << 17);
  }
}

// ---------- B: per-range CSR build + meta/dinv (all LDS atomics) ----------
__global__ void k_build(const u32* __restrict__ part, const int* __restrict__ rangecnt,
                        const int* __restrict__ rangebase, int4* __restrict__ meta,
                        float* __restrict__ dinv, int* __restrict__ csr, int n){
  __shared__ int hist[RSIZE];
  __shared__ int scanx[RSIZE];
  __shared__ int fill[RSIZE];
  int r = blockIdx.x;
  int ne = rangecnt[r], base = rangebase[r];
  int t = threadIdx.x;
  hist[t] = 0;
  __syncthreads();
  for (int i = t; i < ne; i += 256) atomicAdd(&hist[part[base + i] >> 17], 1);
  __syncthreads();
  int v = hist[t];
  scanx[t] = v;
  __syncthreads();
  for (int o = 1; o < 256; o <<= 1){
    int tv = (t >= o) ? scanx[t - o] : 0;
    __syncthreads();
    scanx[t] += tv;
    __syncthreads();
  }
  int excl = scanx[t] - v;
  int node = (r << RBITS) + t;
  if (node < n){
    float di = rsqrtf(1.0f + (float)v);
    meta[node] = make_int4(base + excl, v, __float_as_int(di), 0);
    dinv[node] = di;
  }
  fill[t] = 0;
  scanx[t] = excl;
  __syncthreads();
  for (int i = t; i < ne; i += 256){
    u32 p = part[base + i];
    int dl = (int)(p >> 17);
    int pos = scanx[dl] + atomicAdd(&fill[dl], 1);
    csr[base + pos] = (int)(p & 0x1FFFFu);
  }
}

// ---------- weighted edge list: ew[e] = (src, dinv[src]) ----------
__global__ void k_makeew(const int* __restrict__ csr, const float* __restrict__ dinv,
                         uint2* __restrict__ ew, int E){
  int e = blockIdx.x * 256 + threadIdx.x;
  if (e < E){
    int s = csr[e];
    ew[e] = make_uint2((u32)s, __float_as_uint(dinv[s]));
  }
}

// ---------- degree-sorted node permutation (counting sort, LDS-batched) ----------
__global__ void k_deghist(const int4* __restrict__ meta, int* __restrict__ dhist, int n){
  __shared__ int h[DBINS];
  if (threadIdx.x < DBINS) h[threadIdx.x] = 0;
  __syncthreads();
  int i = blockIdx.x * 256 + threadIdx.x;
  if (i < n) atomicAdd(&h[min(meta[i].y, DBINS - 1)], 1);
  __syncthreads();
  if (threadIdx.x < DBINS && h[threadIdx.x])
    atomicAdd(&dhist[threadIdx.x], h[threadIdx.x]);
}

__global__ void k_degscan(const int* __restrict__ dhist, int* __restrict__ dbase){
  if (threadIdx.x == 0){
    int acc = 0;
    for (int i = 0; i < DBINS; i++){ dbase[i] = acc; acc += dhist[i]; }
  }
}

__global__ void k_degplace(const int4* __restrict__ meta, const int* __restrict__ dbase,
                           int* __restrict__ dfill, int* __restrict__ perm, int n){
  __shared__ int h[DBINS], lbase[DBINS];
  if (threadIdx.x < DBINS) h[threadIdx.x] = 0;
  __syncthreads();
  int i = blockIdx.x * 256 + threadIdx.x;
  int d = 0;
  if (i < n){
    d = min(meta[i].y, DBINS - 1);
    atomicAdd(&h[d], 1);
  }
  __syncthreads();
  if (threadIdx.x < DBINS){
    int c = h[threadIdx.x];
    lbase[threadIdx.x] = c ? dbase[threadIdx.x] + atomicAdd(&dfill[threadIdx.x], c) : 0;
    h[threadIdx.x] = 0;
  }
  __syncthreads();
  if (i < n){
    int pos = lbase[d] + atomicAdd(&h[d], 1);
    perm[pos] = i;
  }
}

// ---------- MFMA GEMM: 128-row x COLS tile, K=128, bf16 in/out, fp32 acc ----------
// Verified fragment layouts (learn_hip m89): A lane l: row=l&15, k=(l>>4)*8+0..7;
// B lane l: col=l&15, same k; C/D lane l: col=l&15, row=(l>>4)*4+reg.
// LDS: Xl[128][136] bf16 + Wt[COLS][136] bf16 (W transposed -> B-frag = 1 ds_read_b128).
template<int COLS, bool XBF, bool BN>
__launch_bounds__(256, 2)
__global__ void k_gemm_mfma(const void* __restrict__ Xv, const float* __restrict__ W,
                            int ldW, int wcols,
                            const float* __restrict__ scale, const float* __restrict__ shift,
                            u16* __restrict__ Y, int ldY, int col_off, int n, int ntiles){
  constexpr int NT = COLS / 16;          // col tiles per wave
  extern __shared__ u16 dyn_lds[];
  u16* Xl = dyn_lds;                     // [128][136]
  u16* Wt = dyn_lds + 128 * 136;         // [COLS][136]

  const int tid  = threadIdx.x;
  const int lane = tid & 63;
  const int wv   = tid >> 6;             // wave 0..3 -> rows wv*32..wv*32+31

  // stage W transposed (zero-pad cols >= wcols); wcols is a multiple of 4
  const int wf4 = wcols >> 2;
  for (int idx = tid; idx < 128 * (COLS >> 2); idx += 256){
    int k  = idx / (COLS >> 2);
    int c4 = idx % (COLS >> 2);
    float4 v = make_float4(0.f, 0.f, 0.f, 0.f);
    if (c4 < wf4) v = *(const float4*)(W + (size_t)k * ldW + (c4 << 2));
    int c = c4 << 2;
    Wt[(c    ) * 136 + k] = f2b(v.x);
    Wt[(c + 1) * 136 + k] = f2b(v.y);
    Wt[(c + 2) * 136 + k] = f2b(v.z);
    Wt[(c + 3) * 136 + k] = f2b(v.w);
  }

  float sc8[8], sh8[8];
  if (BN){
    int c0 = (tid & 15) << 3;
    #pragma unroll
    for (int j = 0; j < 8; j++){ sc8[j] = scale[c0 + j]; sh8[j] = shift[c0 + j]; }
  }

  const int frow = lane & 15;
  const int fk   = (lane >> 4) << 3;     // 0,8,16,24

  for (int t = blockIdx.x; t < ntiles; t += gridDim.x){
    const int r0 = t << 7;
    __syncthreads();   // protects Xl (prev readers) and covers Wt on first iter
    // stage X tile (bf16, optional fused BN+ReLU)
    for (int idx = tid; idx < 128 * 16; idx += 256){
      int row = idx >> 4, c8 = idx & 15;
      int gr = r0 + row;
      float x[8];
      if (gr < n){
        if (XBF){
          const u16* p = (const u16*)Xv + ((size_t)gr << 7) + (c8 << 3);
          uint4 u = *(const uint4*)p;
          x[0] = b2f((u16)u.x); x[1] = b2f((u16)(u.x >> 16));
          x[2] = b2f((u16)u.y); x[3] = b2f((u16)(u.y >> 16));
          x[4] = b2f((u16)u.z); x[5] = b2f((u16)(u.z >> 16));
          x[6] = b2f((u16)u.w); x[7] = b2f((u16)(u.w >> 16));
        } else {
          const float* p = (const float*)Xv + ((size_t)gr << 7) + (c8 << 3);
          float4 a = *(const float4*)p;
          float4 b = *(const float4*)(p + 4);
          x[0]=a.x; x[1]=a.y; x[2]=a.z; x[3]=a.w;
          x[4]=b.x; x[5]=b.y; x[6]=b.z; x[7]=b.w;
        }
        if (BN){
          #pragma unroll
          for (int j = 0; j < 8; j++)
            x[j] = fmaxf(fmaf(x[j], sc8[j], sh8[j]), 0.f);
        }
      } else {
        #pragma unroll
        for (int j = 0; j < 8; j++) x[j] = 0.f;
      }
      uint4 u;
      u.x = (u32)f2b(x[0]) | ((u32)f2b(x[1]) << 16);
      u.y = (u32)f2b(x[2]) | ((u32)f2b(x[3]) << 16);
      u.z = (u32)f2b(x[4]) | ((u32)f2b(x[5]) << 16);
      u.w = (u32)f2b(x[6]) | ((u32)f2b(x[7]) << 16);
      *(uint4*)(Xl + row * 136 + (c8 << 3)) = u;
    }
    __syncthreads();

    f32x4 acc[2][NT];
    #pragma unroll
    for (int i = 0; i < 2; i++)
      #pragma unroll
      for (int j = 0; j < NT; j++)
        acc[i][j] = (f32x4){0.f, 0.f, 0.f, 0.f};

    #pragma unroll
    for (int ks = 0; ks < 4; ks++){
      const int ko = (ks << 5) + fk;
      short8v a0 = *(const short8v*)(Xl + (wv * 32      + frow) * 136 + ko);
      short8v a1 = *(const short8v*)(Xl + (wv * 32 + 16 + frow) * 136 + ko);
      short8v b[NT];
      #pragma unroll
      for (int j = 0; j < NT; j++)
        b[j] = *(const short8v*)(Wt + (j * 16 + frow) * 136 + ko);
      #pragma unroll
      for (int j = 0; j < NT; j++){
        acc[0][j] = __builtin_amdgcn_mfma_f32_16x16x32_bf16(a0, b[j], acc[0][j], 0, 0, 0);
        acc[1][j] = __builtin_amdgcn_mfma_f32_16x16x32_bf16(a1, b[j], acc[1][j], 0, 0, 0);
      }
    }

    // store: D lane l -> col=l&15, rows (l>>4)*4+0..3 of each 16x16 tile
    #pragma unroll
    for (int i = 0; i < 2; i++){
      #pragma unroll
      for (int j = 0; j < NT; j++){
        int cbase = j * 16 + (lane & 15);
        if (cbase < wcols){
          int grow = r0 + wv * 32 + i * 16 + ((lane >> 4) << 2);
          #pragma unroll
          for (int r = 0; r < 4; r++){
            if (grow + r < n)
              Y[(size_t)(grow + r) * ldY + col_off + cbase] = f2b(acc[i][j][r]);
          }
        }
      }
    }
  }
}

// ---------- aggregation (CSR gather, packed edges, degree-sorted order) ----------
__global__ void k_agg128(const u16* __restrict__ H, u16* __restrict__ Y,
                         const int4* __restrict__ meta, const uint2* __restrict__ ew,
                         const int* __restrict__ perm, int n){
  int t = blockIdx.x * 256 + threadIdx.x;
  int g = t >> 4, c8 = t & 15;
  if (g >= n) return;
  const int node = perm[g];
  const int4 m = meta[node];
  const int beg = m.x, num = m.y;
  const float di = __int_as_float(m.z);
  float acc[8];
  {
    uint4 u = *(const uint4*)(H + ((size_t)node << 7) + (c8 << 3));
    acc[0] = b2f((u16)u.x) * di; acc[1] = b2f((u16)(u.x >> 16)) * di;
    acc[2] = b2f((u16)u.y) * di; acc[3] = b2f((u16)(u.y >> 16)) * di;
    acc[4] = b2f((u16)u.z) * di; acc[5] = b2f((u16)(u.z >> 16)) * di;
    acc[6] = b2f((u16)u.w) * di; acc[7] = b2f((u16)(u.w >> 16)) * di;
  }
  int i = 0;
  if ((beg & 1) && num > 0){           // align to even for uint4 ew loads
    uint2 p = ew[beg];
    acc8(acc, *(const uint4*)(H + ((size_t)p.x << 7) + (c8 << 3)), __uint_as_float(p.y));
    i = 1;
  }
  for (; i + 8 <= num; i += 8){
    uint4 p0 = *(const uint4*)(ew + beg + i);
    uint4 p1 = *(const uint4*)(ew + beg + i + 2);
    uint4 p2 = *(const uint4*)(ew + beg + i + 4);
    uint4 p3 = *(const uint4*)(ew + beg + i + 6);
    uint4 h0 = *(const uint4*)(H + ((size_t)p0.x << 7) + (c8 << 3));
    uint4 h1 = *(const uint4*)(H + ((size_t)p0.z << 7) + (c8 << 3));
    uint4 h2 = *(const uint4*)(H + ((size_t)p1.x << 7) + (c8 << 3));
    uint4 h3 = *(const uint4*)(H + ((size_t)p1.z << 7) + (c8 << 3));
    uint4 h4 = *(const uint4*)(H + ((size_t)p2.x << 7) + (c8 << 3));
    uint4 h5 = *(const uint4*)(H + ((size_t)p2.z << 7) + (c8 << 3));
    uint4 h6 = *(const uint4*)(H + ((size_t)p3.x << 7) + (c8 << 3));
    uint4 h7 = *(const uint4*)(H + ((size_t)p3.z << 7) + (c8 << 3));
    acc8(acc, h0, __uint_as_float(p0.y));
    acc8(acc, h1, __uint_as_float(p0.w));
    acc8(acc, h2, __uint_as_float(p1.y));
    acc8(acc, h3, __uint_as_float(p1.w));
    acc8(acc, h4, __uint_as_float(p2.y));
    acc8(acc, h5, __uint_as_float(p2.w));
    acc8(acc, h6, __uint_as_float(p3.y));
    acc8(acc, h7, __uint_as_float(p3.w));
  }
  if (i + 4 <= num){
    uint4 p0 = *(const uint4*)(ew + beg + i);
    uint4 p1 = *(const uint4*)(ew + beg + i + 2);
    uint4 h0 = *(const uint4*)(H + ((size_t)p0.x << 7) + (c8 << 3));
    uint4 h1 = *(const uint4*)(H + ((size_t)p0.z << 7) + (c8 << 3));
    uint4 h2 = *(const uint4*)(H + ((size_t)p1.x << 7) + (c8 << 3));
    uint4 h3 = *(const uint4*)(H + ((size_t)p1.z << 7) + (c8 << 3));
    acc8(acc, h0, __uint_as_float(p0.y));
    acc8(acc, h1, __uint_as_float(p0.w));
    acc8(acc, h2, __uint_as_float(p1.y));
    acc8(acc, h3, __uint_as_float(p1.w));
    i += 4;
  }
  if (i + 2 <= num){
    uint4 p = *(const uint4*)(ew + beg + i);
    uint4 a = *(const uint4*)(H + ((size_t)p.x << 7) + (c8 << 3));
    uint4 b = *(const uint4*)(H + ((size_t)p.z << 7) + (c8 << 3));
    acc8(acc, a, __uint_as_float(p.y));
    acc8(acc, b, __uint_as_float(p.w));
    i += 2;
  }
  if (i < num){
    uint2 p = ew[beg + i];
    acc8(acc, *(const uint4*)(H + ((size_t)p.x << 7) + (c8 << 3)), __uint_as_float(p.y));
  }
  uint4 o;
  o.x = (u32)f2b(acc[0] * di) | ((u32)f2b(acc[1] * di) << 16);
  o.y = (u32)f2b(acc[2] * di) | ((u32)f2b(acc[3] * di) << 16);
  o.z = (u32)f2b(acc[4] * di) | ((u32)f2b(acc[5] * di) << 16);
  o.w = (u32)f2b(acc[6] * di) | ((u32)f2b(acc[7] * di) << 16);
  *(uint4*)(Y + ((size_t)node << 7) + (c8 << 3)) = o;
}

__global__ void k_agg40(const u16* __restrict__ H, const float* __restrict__ bout,
                        float* __restrict__ Y, const int4* __restrict__ meta,
                        const uint2* __restrict__ ew, const int* __restrict__ perm, int n){
  int t = blockIdx.x * 256 + threadIdx.x;
  int g = t >> 4, c4 = t & 15;
  if (g >= n || c4 >= 10) return;
  const int node = perm[g];
  const int4 m = meta[node];
  const int beg = m.x, num = m.y;
  const float di = __int_as_float(m.z);
  float acc[4];
  {
    uint2 u = *(const uint2*)(H + (size_t)node * NOUT + (c4 << 2));
    acc[0] = b2f((u16)u.x) * di; acc[1] = b2f((u16)(u.x >> 16)) * di;
    acc[2] = b2f((u16)u.y) * di; acc[3] = b2f((u16)(u.y >> 16)) * di;
  }
  int i = 0;
  if ((beg & 1) && num > 0){
    uint2 p = ew[beg];
    acc4(acc, *(const uint2*)(H + (size_t)p.x * NOUT + (c4 << 2)), __uint_as_float(p.y));
    i = 1;
  }
  for (; i + 4 <= num; i += 4){
    uint4 p0 = *(const uint4*)(ew + beg + i);
    uint4 p1 = *(const uint4*)(ew + beg + i + 2);
    uint2 a = *(const uint2*)(H + (size_t)p0.x * NOUT + (c4 << 2));
    uint2 b = *(const uint2*)(H + (size_t)p0.z * NOUT + (c4 << 2));
    uint2 c = *(const uint2*)(H + (size_t)p1.x * NOUT + (c4 << 2));
    uint2 d = *(const uint2*)(H + (size_t)p1.z * NOUT + (c4 << 2));
    acc4(acc, a, __uint_as_float(p0.y));
    acc4(acc, b, __uint_as_float(p0.w));
    acc4(acc, c, __uint_as_float(p1.y));
    acc4(acc, d, __uint_as_float(p1.w));
  }
  if (i + 2 <= num){
    uint4 p = *(const uint4*)(ew + beg + i);
    uint2 a = *(const uint2*)(H + (size_t)p.x * NOUT + (c4 << 2));
    uint2 b = *(const uint2*)(H + (size_t)p.z * NOUT + (c4 << 2));
    acc4(acc, a, __uint_as_float(p.y));
    acc4(acc, b, __uint_as_float(p.w));
    i += 2;
  }
  if (i < num){
    uint2 p = ew[beg + i];
    acc4(acc, *(const uint2*)(H + (size_t)p.x * NOUT + (c4 << 2)), __uint_as_float(p.y));
  }
  float4 bb = *(const float4*)(bout + (c4 << 2));
  float4 o;
  o.x = fmaf(acc[0], di, bb.x); o.y = fmaf(acc[1], di, bb.y);
  o.z = fmaf(acc[2], di, bb.z); o.w = fmaf(acc[3], di, bb.w);
  *(float4*)(Y + (size_t)node * NOUT + (c4 << 2)) = o;
}

// ---------- BatchNorm stats (bf16 input) ----------
__global__ void k_bn_stats(const u16* __restrict__ X, float* __restrict__ sum,
                           float* __restrict__ sq, int n){
  int c = threadIdx.x & 127, half = threadIdx.x >> 7;
  float s = 0.f, q = 0.f;
  for (int r = blockIdx.x * 2 + half; r < n; r += gridDim.x * 2){
    float v = b2f(X[((size_t)r << 7) + c]);
    s += v; q = fmaf(v, v, q);
  }
  __shared__ float ls[256], lq[256];
  ls[threadIdx.x] = s; lq[threadIdx.x] = q;
  __syncthreads();
  if (threadIdx.x < 128){
    s = ls[threadIdx.x] + ls[threadIdx.x + 128];
    q = lq[threadIdx.x] + lq[threadIdx.x + 128];
    atomicAdd(&sum[c], s); atomicAdd(&sq[c], q);
  }
}

__global__ void k_bn_fin(const float* __restrict__ sum, const float* __restrict__ sq,
                         const float* __restrict__ g, const float* __restrict__ beta,
                         float* __restrict__ scale, float* __restrict__ shift, int n){
  int c = threadIdx.x;
  if (c < 128){
    float invn = 1.0f / (float)n;
    float mu  = sum[c] * invn;
    float var = sq[c] * invn - mu * mu;
    var = var > 0.f ? var : 0.f;
    float sc = g[c] * rsqrtf(var + BN_EPS);
    scale[c] = sc;
    shift[c] = beta[c] - mu * sc;
  }
}

// ---------- launch ----------
extern "C" void kernel_launch(void* const* d_in, const int* in_sizes, int n_in,
                              void* d_out, int out_size, void* d_ws, size_t ws_size,
                              hipStream_t stream) {
  const float* x0        = (const float*)d_in[0];
  const float* x1        = (const float*)d_in[1];
  const int*   ei        = (const int*)  d_in[2];
  const float* W_init    = (const float*)d_in[3];
  const float* g_init    = (const float*)d_in[5];
  const float* beta_init = (const float*)d_in[6];
  const float* W_mid     = (const float*)d_in[7];
  const float* g_mid     = (const float*)d_in[9];
  const float* beta_mid  = (const float*)d_in[10];
  const float* W_out     = (const float*)d_in[11];
  const float* b_out     = (const float*)d_in[12];

  int N = in_sizes[0] / F_IN;
  int E = in_sizes[2] / 2;
  const int* esrc = ei;
  const int* edst = ei + E;
  int NR = (N + RSIZE - 1) >> RBITS;

  char* w = (char*)d_ws;
  size_t off = 0;
  auto take = [&](size_t bytes) -> char* {
    char* p = w + off;
    off = (off + bytes + 255) & ~(size_t)255;
    return p;
  };
  float* dinv      = (float*)take((size_t)N * 4);
  int4*  meta      = (int4*) take((size_t)N * 16);
  int*   perm      = (int*)  take((size_t)N * 4);
  // single zeroed block: rangecnt(512) | rangefill(512) | dhist(64) | dfill(64) | stats(1024)
  int*   zeroblk   = (int*)  take((size_t)2176 * 4);
  int*   rangecnt  = zeroblk;
  int*   rangefill = zeroblk + 512;
  int*   dhist     = zeroblk + 1024;
  int*   dfill     = zeroblk + 1088;
  float* stats     = (float*)(zeroblk + 1152);
  int*   rangebase = (int*)  take((size_t)MAXNR * 4);
  int*   dbase     = (int*)  take((size_t)DBINS * 4);
  u32*   part      = (u32*)  take((size_t)E * 4);
  int*   csr       = (int*)  take((size_t)E * 4);
  uint2* ew        = (uint2*)take((size_t)E * 8);
  u16*   A         = (u16*)  take((size_t)N * 128 * 2);
  u16*   B         = (u16*)  take((size_t)N * 128 * 2);
  (void)ws_size; (void)n_in; (void)out_size;

  float* sum1 = stats,       *sq1 = stats + 128, *scale1 = stats + 256, *shift1 = stats + 384;
  float* sum2 = stats + 512, *sq2 = stats + 640, *scale2 = stats + 768, *shift2 = stats + 896;

  hipMemsetAsync(zeroblk, 0, (size_t)2176 * 4, stream);

  // CSR build via range partition (no global per-edge atomics)
  const int PB = 512;
  const int chunk = ceil_div_l(E, PB);
  const int NBn = ceil_div_l(N, 256);
  k_rangecount<<<PB, 256, 0, stream>>>(edst, rangecnt, E, NR, chunk);
  k_rangescan <<<1, MAXNR, 0, stream>>>(rangecnt, rangebase, NR);
  k_partition <<<PB, 256, 0, stream>>>(esrc, edst, rangebase, rangefill, part, E, NR, chunk);
  k_build     <<<NR, RSIZE, 0, stream>>>(part, rangecnt, rangebase, meta, dinv, csr, N);
  k_makeew    <<<ceil_div_l(E,256), 256, 0, stream>>>(csr, dinv, ew, E);
  // degree-sorted permutation (equal-degree nodes share a wave -> no divergence waste)
  k_deghist <<<NBn, 256, 0, stream>>>(meta, dhist, N);
  k_degscan <<<1, 64, 0, stream>>>(dhist, dbase);
  k_degplace<<<NBn, 256, 0, stream>>>(meta, dbase, dfill, perm, N);

  const int ntiles = ceil_div_l(N, 128);
  const int AGB = ceil_div_l(N, 16);       // agg blocks (16 nodes x 16 lanes)
  const size_t lds64  = (size_t)(128 * 136 + 64  * 136) * 2;  // 52224 B
  const size_t lds128 = (size_t)(128 * 136 + 128 * 136) * 2;  // 69632 B

  // layer 1: two branch GEMMs into concat layout
  k_gemm_mfma<64,false,false><<<768,256,lds64,stream>>>(x0, W_init,          64, 64, nullptr, nullptr, A, 128,  0, N, ntiles);
  k_gemm_mfma<64,false,false><<<768,256,lds64,stream>>>(x1, W_init + 128*64, 64, 64, nullptr, nullptr, A, 128, 64, N, ntiles);
  k_agg128<<<AGB,256,0,stream>>>(A, B, meta, ew, perm, N);
  k_bn_stats<<<512,256,0,stream>>>(B, sum1, sq1, N);
  k_bn_fin<<<1,128,0,stream>>>(sum1, sq1, g_init, beta_init, scale1, shift1, N);

  // layer 2: single 128-col MFMA GEMM (BN1+ReLU fused into staging)
  k_gemm_mfma<128,true,true><<<512,256,lds128,stream>>>(B, W_mid, 128, 128, scale1, shift1, A, 128, 0, N, ntiles);
  k_agg128<<<AGB,256,0,stream>>>(A, B, meta, ew, perm, N);
  k_bn_stats<<<512,256,0,stream>>>(B, sum2, sq2, N);
  k_bn_fin<<<1,128,0,stream>>>(sum2, sq2, g_mid, beta_mid, scale2, shift2, N);

  // layer 3: BN2+ReLU fused; 40 cols (zero-padded to 64 in LDS), compact bf16 out
  k_gemm_mfma<64,true,true><<<768,256,lds64,stream>>>(B, W_out, 40, 40, scale2, shift2, A, 40, 0, N, ntiles);
  k_agg40<<<AGB,256,0,stream>>>(A, b_out, (float*)d_out, meta, ew, perm, N);
}

// Round 8
// 345.886 us; speedup vs baseline: 2.0387x; 1.1913x over previous
//
#include <hip/hip_runtime.h>
#include <cstdint>
#include <cstddef>

#define F_IN 128
#define NOUT 40
#define BN_EPS 1e-5f
#define RBITS 8
#define RSIZE 256           // nodes per range
#define MAXNR 512           // supports N <= 131072
#define DBINS 64            // degree-sort bins (cap 63)

typedef unsigned short u16;
typedef unsigned int u32;
typedef __attribute__((ext_vector_type(8))) short short8v;  // 8 bf16 (4 VGPR)
typedef __attribute__((ext_vector_type(4))) float f32x4;

static inline int ceil_div_l(long a, long b){ return (int)((a + b - 1) / b); }

__device__ __forceinline__ float b2f(u16 h){
  union { u32 u; float f; } v; v.u = ((u32)h) << 16; return v.f;
}
__device__ __forceinline__ u16 f2b(float x){
  union { float f; u32 u; } v; v.f = x;
  u32 r = v.u + 0x7FFFu + ((v.u >> 16) & 1u);
  return (u16)(r >> 16);
}
__device__ __forceinline__ void acc8(float* acc, uint4 u, float w){
  acc[0] = fmaf(b2f((u16)u.x),         w, acc[0]);
  acc[1] = fmaf(b2f((u16)(u.x >> 16)), w, acc[1]);
  acc[2] = fmaf(b2f((u16)u.y),         w, acc[2]);
  acc[3] = fmaf(b2f((u16)(u.y >> 16)), w, acc[3]);
  acc[4] = fmaf(b2f((u16)u.z),         w, acc[4]);
  acc[5] = fmaf(b2f((u16)(u.z >> 16)), w, acc[5]);
  acc[6] = fmaf(b2f((u16)u.w),         w, acc[6]);
  acc[7] = fmaf(b2f((u16)(u.w >> 16)), w, acc[7]);
}
__device__ __forceinline__ void acc4(float* acc, uint2 u, float w){
  acc[0] = fmaf(b2f((u16)u.x),         w, acc[0]);
  acc[1] = fmaf(b2f((u16)(u.x >> 16)), w, acc[1]);
  acc[2] = fmaf(b2f((u16)u.y),         w, acc[2]);
  acc[3] = fmaf(b2f((u16)(u.y >> 16)), w, acc[3]);
}

// ---------- A1: per-range edge counts (LDS histogram) ----------
__global__ void k_rangecount(const int* __restrict__ dst, int* __restrict__ rangecnt,
                             int E, int NR, int chunk){
  __shared__ u32 hist[MAXNR];
  for (int i = threadIdx.x; i < NR; i += 256) hist[i] = 0;
  __syncthreads();
  int s = blockIdx.x * chunk;
  int e_end = min(s + chunk, E);
  for (int e = s + threadIdx.x; e < e_end; e += 256)
    atomicAdd(&hist[(u32)dst[e] >> RBITS], 1u);
  __syncthreads();
  for (int i = threadIdx.x; i < NR; i += 256){
    u32 h = hist[i];
    if (h) atomicAdd((u32*)&rangecnt[i], h);
  }
}

// ---------- A2: exclusive scan of range counts ----------
__global__ void k_rangescan(const int* __restrict__ rangecnt, int* __restrict__ rangebase,
                            int NR){
  __shared__ int s[MAXNR];
  int t = threadIdx.x;
  if (t < NR) s[t] = rangecnt[t];
  __syncthreads();
  if (t == 0){
    int acc = 0;
    for (int i = 0; i < NR; i++){ int v = s[i]; s[i] = acc; acc += v; }
  }
  __syncthreads();
  if (t < NR) rangebase[t] = s[t];
}

// ---------- A3: partition edges into per-range segments (packed u32) ----------
__global__ void k_partition(const int* __restrict__ src, const int* __restrict__ dst,
                            const int* __restrict__ rangebase, int* __restrict__ rangefill,
                            u32* __restrict__ part, int E, int NR, int chunk){
  __shared__ u32 hist[MAXNR];
  __shared__ u32 lbase[MAXNR];
  for (int i = threadIdx.x; i < NR; i += 256) hist[i] = 0;
  __syncthreads();
  int s0 = blockIdx.x * chunk;
  int e_end = min(s0 + chunk, E);
  for (int e = s0 + threadIdx.x; e < e_end; e += 256)
    atomicAdd(&hist[(u32)dst[e] >> RBITS], 1u);
  __syncthreads();
  for (int i = threadIdx.x; i < NR; i += 256){
    u32 h = hist[i];
    u32 b = h ? (u32)atomicAdd((u32*)&rangefill[i], h) : 0u;
    lbase[i] = (u32)rangebase[i] + b;
    hist[i] = 0;                       // reuse as local fill
  }
  __syncthreads();
  for (int e = s0 + threadIdx.x; e < e_end; e += 256){
    u32 d = (u32)dst[e];
    u32 r = d >> RBITS;
    u32 pos = lbase[r] + atomicAdd(&hist[r], 1u);
    part[pos] = (u32)src[e] | ((d & (RSIZE - 1)) << 17);
  }
}

// ---------- B: per-range CSR build + meta/dinv + degree histogram (LDS atomics) ----------
__global__ void k_build(const u32* __restrict__ part, const int* __restrict__ rangecnt,
                        const int* __restrict__ rangebase, int4* __restrict__ meta,
                        float* __restrict__ dinv, int* __restrict__ csr,
                        int* __restrict__ dhist, int n){
  __shared__ int hist[RSIZE];
  __shared__ int scanx[RSIZE];
  __shared__ int fill[RSIZE];
  __shared__ int ldh[DBINS];
  int r = blockIdx.x;
  int ne = rangecnt[r], base = rangebase[r];
  int t = threadIdx.x;
  hist[t] = 0;
  if (t < DBINS) ldh[t] = 0;
  __syncthreads();
  for (int i = t; i < ne; i += 256) atomicAdd(&hist[part[base + i] >> 17], 1);
  __syncthreads();
  int v = hist[t];
  scanx[t] = v;
  __syncthreads();
  for (int o = 1; o < 256; o <<= 1){
    int tv = (t >= o) ? scanx[t - o] : 0;
    __syncthreads();
    scanx[t] += tv;
    __syncthreads();
  }
  int excl = scanx[t] - v;
  int node = (r << RBITS) + t;
  if (node < n){
    float di = rsqrtf(1.0f + (float)v);
    meta[node] = make_int4(base + excl, v, __float_as_int(di), 0);
    dinv[node] = di;
    atomicAdd(&ldh[min(v, DBINS - 1)], 1);   // fused degree histogram
  }
  fill[t] = 0;
  scanx[t] = excl;
  __syncthreads();
  for (int i = t; i < ne; i += 256){
    u32 p = part[base + i];
    int dl = (int)(p >> 17);
    int pos = scanx[dl] + atomicAdd(&fill[dl], 1);
    csr[base + pos] = (int)(p & 0x1FFFFu);
  }
  if (t < DBINS && ldh[t]) atomicAdd(&dhist[t], ldh[t]);
}

// ---------- weighted edge list: ew[e] = (src, dinv[src]); block 0 also scans dhist ----------
__global__ void k_makeew(const int* __restrict__ csr, const float* __restrict__ dinv,
                         uint2* __restrict__ ew, const int* __restrict__ dhist,
                         int* __restrict__ dbase, int E){
  int e = blockIdx.x * 256 + threadIdx.x;
  if (e < E){
    int s = csr[e];
    ew[e] = make_uint2((u32)s, __float_as_uint(dinv[s]));
  }
  if (blockIdx.x == 0 && threadIdx.x == 0){
    int acc = 0;
    for (int i = 0; i < DBINS; i++){ dbase[i] = acc; acc += dhist[i]; }
  }
}

__global__ void k_degplace(const int4* __restrict__ meta, const int* __restrict__ dbase,
                           int* __restrict__ dfill, int* __restrict__ perm, int n){
  __shared__ int h[DBINS], lbase[DBINS];
  if (threadIdx.x < DBINS) h[threadIdx.x] = 0;
  __syncthreads();
  int i = blockIdx.x * 256 + threadIdx.x;
  int d = 0;
  if (i < n){
    d = min(meta[i].y, DBINS - 1);
    atomicAdd(&h[d], 1);
  }
  __syncthreads();
  if (threadIdx.x < DBINS){
    int c = h[threadIdx.x];
    lbase[threadIdx.x] = c ? dbase[threadIdx.x] + atomicAdd(&dfill[threadIdx.x], c) : 0;
    h[threadIdx.x] = 0;
  }
  __syncthreads();
  if (i < n){
    int pos = lbase[d] + atomicAdd(&h[d], 1);
    perm[pos] = i;
  }
}

// ---------- MFMA GEMM: 128-row x COLS tile, K=128, bf16 in/out, fp32 acc ----------
// BN=true: per-block prelude computes scale/shift from 8-striped raw sums (fused bn_fin),
// then applies x*scale+shift, relu during staging.
template<int COLS, bool XBF, bool BN>
__launch_bounds__(256, 2)
__global__ void k_gemm_mfma(const void* __restrict__ Xv, const float* __restrict__ W,
                            int ldW, int wcols,
                            const float* __restrict__ bn_sum, const float* __restrict__ bn_sq,
                            const float* __restrict__ g, const float* __restrict__ beta,
                            u16* __restrict__ Y, int ldY, int col_off, int n, int ntiles){
  constexpr int NT = COLS / 16;          // col tiles per wave
  extern __shared__ u16 dyn_lds[];
  u16* Xl = dyn_lds;                     // [128][136]
  u16* Wt = dyn_lds + 128 * 136;         // [COLS][136]
  __shared__ float sc_l[128], sh_l[128];

  const int tid  = threadIdx.x;
  const int lane = tid & 63;
  const int wv   = tid >> 6;             // wave 0..3 -> rows wv*32..wv*32+31

  if (BN){
    if (tid < 128){
      float s = 0.f, q = 0.f;
      #pragma unroll
      for (int k = 0; k < 8; k++){ s += bn_sum[(k << 7) + tid]; q += bn_sq[(k << 7) + tid]; }
      float invn = 1.0f / (float)n;
      float mu  = s * invn;
      float var = q * invn - mu * mu;
      var = var > 0.f ? var : 0.f;
      float sc = g[tid] * rsqrtf(var + BN_EPS);
      sc_l[tid] = sc;
      sh_l[tid] = beta[tid] - mu * sc;
    }
    __syncthreads();
  }

  // stage W transposed (zero-pad cols >= wcols); wcols is a multiple of 4
  const int wf4 = wcols >> 2;
  for (int idx = tid; idx < 128 * (COLS >> 2); idx += 256){
    int k  = idx / (COLS >> 2);
    int c4 = idx % (COLS >> 2);
    float4 v = make_float4(0.f, 0.f, 0.f, 0.f);
    if (c4 < wf4) v = *(const float4*)(W + (size_t)k * ldW + (c4 << 2));
    int c = c4 << 2;
    Wt[(c    ) * 136 + k] = f2b(v.x);
    Wt[(c + 1) * 136 + k] = f2b(v.y);
    Wt[(c + 2) * 136 + k] = f2b(v.z);
    Wt[(c + 3) * 136 + k] = f2b(v.w);
  }

  float sc8[8], sh8[8];
  if (BN){
    int c0 = (tid & 15) << 3;
    #pragma unroll
    for (int j = 0; j < 8; j++){ sc8[j] = sc_l[c0 + j]; sh8[j] = sh_l[c0 + j]; }
  }

  const int frow = lane & 15;
  const int fk   = (lane >> 4) << 3;     // 0,8,16,24

  for (int t = blockIdx.x; t < ntiles; t += gridDim.x){
    const int r0 = t << 7;
    __syncthreads();   // protects Xl (prev readers) and covers Wt on first iter
    // stage X tile (bf16, optional fused BN+ReLU)
    for (int idx = tid; idx < 128 * 16; idx += 256){
      int row = idx >> 4, c8 = idx & 15;
      int gr = r0 + row;
      float x[8];
      if (gr < n){
        if (XBF){
          const u16* p = (const u16*)Xv + ((size_t)gr << 7) + (c8 << 3);
          uint4 u = *(const uint4*)p;
          x[0] = b2f((u16)u.x); x[1] = b2f((u16)(u.x >> 16));
          x[2] = b2f((u16)u.y); x[3] = b2f((u16)(u.y >> 16));
          x[4] = b2f((u16)u.z); x[5] = b2f((u16)(u.z >> 16));
          x[6] = b2f((u16)u.w); x[7] = b2f((u16)(u.w >> 16));
        } else {
          const float* p = (const float*)Xv + ((size_t)gr << 7) + (c8 << 3);
          float4 a = *(const float4*)p;
          float4 b = *(const float4*)(p + 4);
          x[0]=a.x; x[1]=a.y; x[2]=a.z; x[3]=a.w;
          x[4]=b.x; x[5]=b.y; x[6]=b.z; x[7]=b.w;
        }
        if (BN){
          #pragma unroll
          for (int j = 0; j < 8; j++)
            x[j] = fmaxf(fmaf(x[j], sc8[j], sh8[j]), 0.f);
        }
      } else {
        #pragma unroll
        for (int j = 0; j < 8; j++) x[j] = 0.f;
      }
      uint4 u;
      u.x = (u32)f2b(x[0]) | ((u32)f2b(x[1]) << 16);
      u.y = (u32)f2b(x[2]) | ((u32)f2b(x[3]) << 16);
      u.z = (u32)f2b(x[4]) | ((u32)f2b(x[5]) << 16);
      u.w = (u32)f2b(x[6]) | ((u32)f2b(x[7]) << 16);
      *(uint4*)(Xl + row * 136 + (c8 << 3)) = u;
    }
    __syncthreads();

    f32x4 acc[2][NT];
    #pragma unroll
    for (int i = 0; i < 2; i++)
      #pragma unroll
      for (int j = 0; j < NT; j++)
        acc[i][j] = (f32x4){0.f, 0.f, 0.f, 0.f};

    #pragma unroll
    for (int ks = 0; ks < 4; ks++){
      const int ko = (ks << 5) + fk;
      short8v a0 = *(const short8v*)(Xl + (wv * 32      + frow) * 136 + ko);
      short8v a1 = *(const short8v*)(Xl + (wv * 32 + 16 + frow) * 136 + ko);
      short8v b[NT];
      #pragma unroll
      for (int j = 0; j < NT; j++)
        b[j] = *(const short8v*)(Wt + (j * 16 + frow) * 136 + ko);
      #pragma unroll
      for (int j = 0; j < NT; j++){
        acc[0][j] = __builtin_amdgcn_mfma_f32_16x16x32_bf16(a0, b[j], acc[0][j], 0, 0, 0);
        acc[1][j] = __builtin_amdgcn_mfma_f32_16x16x32_bf16(a1, b[j], acc[1][j], 0, 0, 0);
      }
    }

    // store: D lane l -> col=l&15, rows (l>>4)*4+0..3 of each 16x16 tile
    #pragma unroll
    for (int i = 0; i < 2; i++){
      #pragma unroll
      for (int j = 0; j < NT; j++){
        int cbase = j * 16 + (lane & 15);
        if (cbase < wcols){
          int grow = r0 + wv * 32 + i * 16 + ((lane >> 4) << 2);
          #pragma unroll
          for (int r = 0; r < 4; r++){
            if (grow + r < n)
              Y[(size_t)(grow + r) * ldY + col_off + cbase] = f2b(acc[i][j][r]);
          }
        }
      }
    }
  }
}

// ---------- aggregation (CSR gather, packed edges, degree-sorted order) ----------
__global__ void k_agg128(const u16* __restrict__ H, u16* __restrict__ Y,
                         const int4* __restrict__ meta, const uint2* __restrict__ ew,
                         const int* __restrict__ perm, int n){
  int t = blockIdx.x * 256 + threadIdx.x;
  int g = t >> 4, c8 = t & 15;
  if (g >= n) return;
  const int node = perm[g];
  const int4 m = meta[node];
  const int beg = m.x, num = m.y;
  const float di = __int_as_float(m.z);
  float acc[8];
  {
    uint4 u = *(const uint4*)(H + ((size_t)node << 7) + (c8 << 3));
    acc[0] = b2f((u16)u.x) * di; acc[1] = b2f((u16)(u.x >> 16)) * di;
    acc[2] = b2f((u16)u.y) * di; acc[3] = b2f((u16)(u.y >> 16)) * di;
    acc[4] = b2f((u16)u.z) * di; acc[5] = b2f((u16)(u.z >> 16)) * di;
    acc[6] = b2f((u16)u.w) * di; acc[7] = b2f((u16)(u.w >> 16)) * di;
  }
  int i = 0;
  if ((beg & 1) && num > 0){           // align to even for uint4 ew loads
    uint2 p = ew[beg];
    acc8(acc, *(const uint4*)(H + ((size_t)p.x << 7) + (c8 << 3)), __uint_as_float(p.y));
    i = 1;
  }
  for (; i + 8 <= num; i += 8){
    uint4 p0 = *(const uint4*)(ew + beg + i);
    uint4 p1 = *(const uint4*)(ew + beg + i + 2);
    uint4 p2 = *(const uint4*)(ew + beg + i + 4);
    uint4 p3 = *(const uint4*)(ew + beg + i + 6);
    uint4 h0 = *(const uint4*)(H + ((size_t)p0.x << 7) + (c8 << 3));
    uint4 h1 = *(const uint4*)(H + ((size_t)p0.z << 7) + (c8 << 3));
    uint4 h2 = *(const uint4*)(H + ((size_t)p1.x << 7) + (c8 << 3));
    uint4 h3 = *(const uint4*)(H + ((size_t)p1.z << 7) + (c8 << 3));
    uint4 h4 = *(const uint4*)(H + ((size_t)p2.x << 7) + (c8 << 3));
    uint4 h5 = *(const uint4*)(H + ((size_t)p2.z << 7) + (c8 << 3));
    uint4 h6 = *(const uint4*)(H + ((size_t)p3.x << 7) + (c8 << 3));
    uint4 h7 = *(const uint4*)(H + ((size_t)p3.z << 7) + (c8 << 3));
    acc8(acc, h0, __uint_as_float(p0.y));
    acc8(acc, h1, __uint_as_float(p0.w));
    acc8(acc, h2, __uint_as_float(p1.y));
    acc8(acc, h3, __uint_as_float(p1.w));
    acc8(acc, h4, __uint_as_float(p2.y));
    acc8(acc, h5, __uint_as_float(p2.w));
    acc8(acc, h6, __uint_as_float(p3.y));
    acc8(acc, h7, __uint_as_float(p3.w));
  }
  if (i + 4 <= num){
    uint4 p0 = *(const uint4*)(ew + beg + i);
    uint4 p1 = *(const uint4*)(ew + beg + i + 2);
    uint4 h0 = *(const uint4*)(H + ((size_t)p0.x << 7) + (c8 << 3));
    uint4 h1 = *(const uint4*)(H + ((size_t)p0.z << 7) + (c8 << 3));
    uint4 h2 = *(const uint4*)(H + ((size_t)p1.x << 7) + (c8 << 3));
    uint4 h3 = *(const uint4*)(H + ((size_t)p1.z << 7) + (c8 << 3));
    acc8(acc, h0, __uint_as_float(p0.y));
    acc8(acc, h1, __uint_as_float(p0.w));
    acc8(acc, h2, __uint_as_float(p1.y));
    acc8(acc, h3, __uint_as_float(p1.w));
    i += 4;
  }
  if (i + 2 <= num){
    uint4 p = *(const uint4*)(ew + beg + i);
    uint4 a = *(const uint4*)(H + ((size_t)p.x << 7) + (c8 << 3));
    uint4 b = *(const uint4*)(H + ((size_t)p.z << 7) + (c8 << 3));
    acc8(acc, a, __uint_as_float(p.y));
    acc8(acc, b, __uint_as_float(p.w));
    i += 2;
  }
  if (i < num){
    uint2 p = ew[beg + i];
    acc8(acc, *(const uint4*)(H + ((size_t)p.x << 7) + (c8 << 3)), __uint_as_float(p.y));
  }
  uint4 o;
  o.x = (u32)f2b(acc[0] * di) | ((u32)f2b(acc[1] * di) << 16);
  o.y = (u32)f2b(acc[2] * di) | ((u32)f2b(acc[3] * di) << 16);
  o.z = (u32)f2b(acc[4] * di) | ((u32)f2b(acc[5] * di) << 16);
  o.w = (u32)f2b(acc[6] * di) | ((u32)f2b(acc[7] * di) << 16);
  *(uint4*)(Y + ((size_t)node << 7) + (c8 << 3)) = o;
}

__global__ void k_agg40(const u16* __restrict__ H, const float* __restrict__ bout,
                        float* __restrict__ Y, const int4* __restrict__ meta,
                        const uint2* __restrict__ ew, const int* __restrict__ perm, int n){
  int t = blockIdx.x * 256 + threadIdx.x;
  int g = t >> 4, c4 = t & 15;
  if (g >= n || c4 >= 10) return;
  const int node = perm[g];
  const int4 m = meta[node];
  const int beg = m.x, num = m.y;
  const float di = __int_as_float(m.z);
  float acc[4];
  {
    uint2 u = *(const uint2*)(H + (size_t)node * NOUT + (c4 << 2));
    acc[0] = b2f((u16)u.x) * di; acc[1] = b2f((u16)(u.x >> 16)) * di;
    acc[2] = b2f((u16)u.y) * di; acc[3] = b2f((u16)(u.y >> 16)) * di;
  }
  int i = 0;
  if ((beg & 1) && num > 0){
    uint2 p = ew[beg];
    acc4(acc, *(const uint2*)(H + (size_t)p.x * NOUT + (c4 << 2)), __uint_as_float(p.y));
    i = 1;
  }
  for (; i + 4 <= num; i += 4){
    uint4 p0 = *(const uint4*)(ew + beg + i);
    uint4 p1 = *(const uint4*)(ew + beg + i + 2);
    uint2 a = *(const uint2*)(H + (size_t)p0.x * NOUT + (c4 << 2));
    uint2 b = *(const uint2*)(H + (size_t)p0.z * NOUT + (c4 << 2));
    uint2 c = *(const uint2*)(H + (size_t)p1.x * NOUT + (c4 << 2));
    uint2 d = *(const uint2*)(H + (size_t)p1.z * NOUT + (c4 << 2));
    acc4(acc, a, __uint_as_float(p0.y));
    acc4(acc, b, __uint_as_float(p0.w));
    acc4(acc, c, __uint_as_float(p1.y));
    acc4(acc, d, __uint_as_float(p1.w));
  }
  if (i + 2 <= num){
    uint4 p = *(const uint4*)(ew + beg + i);
    uint2 a = *(const uint2*)(H + (size_t)p.x * NOUT + (c4 << 2));
    uint2 b = *(const uint2*)(H + (size_t)p.z * NOUT + (c4 << 2));
    acc4(acc, a, __uint_as_float(p.y));
    acc4(acc, b, __uint_as_float(p.w));
    i += 2;
  }
  if (i < num){
    uint2 p = ew[beg + i];
    acc4(acc, *(const uint2*)(H + (size_t)p.x * NOUT + (c4 << 2)), __uint_as_float(p.y));
  }
  float4 bb = *(const float4*)(bout + (c4 << 2));
  float4 o;
  o.x = fmaf(acc[0], di, bb.x); o.y = fmaf(acc[1], di, bb.y);
  o.z = fmaf(acc[2], di, bb.z); o.w = fmaf(acc[3], di, bb.w);
  *(float4*)(Y + (size_t)node * NOUT + (c4 << 2)) = o;
}

// ---------- BatchNorm stats (bf16 input, uint4 loads, 8-striped output) ----------
__global__ void k_bn_stats(const u16* __restrict__ X, float* __restrict__ sum8,
                           float* __restrict__ sq8, int n){
  const int tid = threadIdx.x;
  const int c8 = tid & 15, rl = tid >> 4;
  float s[8] = {0,0,0,0,0,0,0,0}, q[8] = {0,0,0,0,0,0,0,0};
  for (int r = blockIdx.x * 16 + rl; r < n; r += gridDim.x * 16){
    uint4 u = *(const uint4*)(X + ((size_t)r << 7) + (c8 << 3));
    float x0 = b2f((u16)u.x), x1 = b2f((u16)(u.x >> 16));
    float x2 = b2f((u16)u.y), x3 = b2f((u16)(u.y >> 16));
    float x4 = b2f((u16)u.z), x5 = b2f((u16)(u.z >> 16));
    float x6 = b2f((u16)u.w), x7 = b2f((u16)(u.w >> 16));
    s[0]+=x0; s[1]+=x1; s[2]+=x2; s[3]+=x3; s[4]+=x4; s[5]+=x5; s[6]+=x6; s[7]+=x7;
    q[0]=fmaf(x0,x0,q[0]); q[1]=fmaf(x1,x1,q[1]); q[2]=fmaf(x2,x2,q[2]); q[3]=fmaf(x3,x3,q[3]);
    q[4]=fmaf(x4,x4,q[4]); q[5]=fmaf(x5,x5,q[5]); q[6]=fmaf(x6,x6,q[6]); q[7]=fmaf(x7,x7,q[7]);
  }
  __shared__ float ls[256 * 8];
  const int sb = (blockIdx.x & 7) << 7;
  #pragma unroll
  for (int j = 0; j < 8; j++) ls[tid * 8 + j] = s[j];
  __syncthreads();
  if (tid < 128){
    float acc = 0.f;
    #pragma unroll
    for (int k = 0; k < 16; k++) acc += ls[(k << 7) + tid];
    atomicAdd(&sum8[sb + tid], acc);
  }
  __syncthreads();
  #pragma unroll
  for (int j = 0; j < 8; j++) ls[tid * 8 + j] = q[j];
  __syncthreads();
  if (tid < 128){
    float acc = 0.f;
    #pragma unroll
    for (int k = 0; k < 16; k++) acc += ls[(k << 7) + tid];
    atomicAdd(&sq8[sb + tid], acc);
  }
}

// ---------- launch ----------
extern "C" void kernel_launch(void* const* d_in, const int* in_sizes, int n_in,
                              void* d_out, int out_size, void* d_ws, size_t ws_size,
                              hipStream_t stream) {
  const float* x0        = (const float*)d_in[0];
  const float* x1        = (const float*)d_in[1];
  const int*   ei        = (const int*)  d_in[2];
  const float* W_init    = (const float*)d_in[3];
  const float* g_init    = (const float*)d_in[5];
  const float* beta_init = (const float*)d_in[6];
  const float* W_mid     = (const float*)d_in[7];
  const float* g_mid     = (const float*)d_in[9];
  const float* beta_mid  = (const float*)d_in[10];
  const float* W_out     = (const float*)d_in[11];
  const float* b_out     = (const float*)d_in[12];

  int N = in_sizes[0] / F_IN;
  int E = in_sizes[2] / 2;
  const int* esrc = ei;
  const int* edst = ei + E;
  int NR = (N + RSIZE - 1) >> RBITS;

  char* w = (char*)d_ws;
  size_t off = 0;
  auto take = [&](size_t bytes) -> char* {
    char* p = w + off;
    off = (off + bytes + 255) & ~(size_t)255;
    return p;
  };
  float* dinv      = (float*)take((size_t)N * 4);
  int4*  meta      = (int4*) take((size_t)N * 16);
  int*   perm      = (int*)  take((size_t)N * 4);
  // single zeroed block: rangecnt(512)|rangefill(512)|dhist(64)|dfill(64)|stats(4096)
  int*   zeroblk   = (int*)  take((size_t)5248 * 4);
  int*   rangecnt  = zeroblk;
  int*   rangefill = zeroblk + 512;
  int*   dhist     = zeroblk + 1024;
  int*   dfill     = zeroblk + 1088;
  float* stats     = (float*)(zeroblk + 1152);
  int*   rangebase = (int*)  take((size_t)MAXNR * 4);
  int*   dbase     = (int*)  take((size_t)DBINS * 4);
  u32*   part      = (u32*)  take((size_t)E * 4);
  int*   csr       = (int*)  take((size_t)E * 4);
  uint2* ew        = (uint2*)take((size_t)E * 8);
  u16*   A         = (u16*)  take((size_t)N * 128 * 2);
  u16*   B         = (u16*)  take((size_t)N * 128 * 2);
  (void)ws_size; (void)n_in; (void)out_size;

  float* sum1 = stats;           // 8x128
  float* sq1  = stats + 1024;
  float* sum2 = stats + 2048;
  float* sq2  = stats + 3072;

  hipMemsetAsync(zeroblk, 0, (size_t)5248 * 4, stream);

  // CSR build via range partition (no global per-edge atomics)
  const int PB = 512;
  const int chunk = ceil_div_l(E, PB);
  const int NBn = ceil_div_l(N, 256);
  k_rangecount<<<PB, 256, 0, stream>>>(edst, rangecnt, E, NR, chunk);
  k_rangescan <<<1, MAXNR, 0, stream>>>(rangecnt, rangebase, NR);
  k_partition <<<PB, 256, 0, stream>>>(esrc, edst, rangebase, rangefill, part, E, NR, chunk);
  k_build     <<<NR, RSIZE, 0, stream>>>(part, rangecnt, rangebase, meta, dinv, csr, dhist, N);
  k_makeew    <<<ceil_div_l(E,256), 256, 0, stream>>>(csr, dinv, ew, dhist, dbase, E);
  k_degplace  <<<NBn, 256, 0, stream>>>(meta, dbase, dfill, perm, N);

  const int ntiles = ceil_div_l(N, 128);
  const int AGB = ceil_div_l(N, 16);       // agg blocks (16 nodes x 16 lanes)
  const size_t lds64  = (size_t)(128 * 136 + 64  * 136) * 2;  // 52224 B
  const size_t lds128 = (size_t)(128 * 136 + 128 * 136) * 2;  // 69632 B

  // layer 1: two branch GEMMs into concat layout
  k_gemm_mfma<64,false,false><<<768,256,lds64,stream>>>(x0, W_init,          64, 64,
      nullptr, nullptr, nullptr, nullptr, A, 128,  0, N, ntiles);
  k_gemm_mfma<64,false,false><<<768,256,lds64,stream>>>(x1, W_init + 128*64, 64, 64,
      nullptr, nullptr, nullptr, nullptr, A, 128, 64, N, ntiles);
  k_agg128<<<AGB,256,0,stream>>>(A, B, meta, ew, perm, N);
  k_bn_stats<<<512,256,0,stream>>>(B, sum1, sq1, N);

  // layer 2: single 128-col MFMA GEMM (bn_fin + BN1 + ReLU fused into prelude/staging)
  k_gemm_mfma<128,true,true><<<512,256,lds128,stream>>>(B, W_mid, 128, 128,
      sum1, sq1, g_init, beta_init, A, 128, 0, N, ntiles);
  k_agg128<<<AGB,256,0,stream>>>(A, B, meta, ew, perm, N);
  k_bn_stats<<<512,256,0,stream>>>(B, sum2, sq2, N);

  // layer 3: bn_fin + BN2 + ReLU fused; 40 cols (zero-padded to 64), compact bf16 out
  k_gemm_mfma<64,true,true><<<768,256,lds64,stream>>>(B, W_out, 40, 40,
      sum2, sq2, g_mid, beta_mid, A, 40, 0, N, ntiles);
  k_agg40<<<AGB,256,0,stream>>>(A, b_out, (float*)d_out, meta, ew, perm, N);
}